// Round 5
// baseline (847.030 us; speedup 1.0000x reference)
//
#include <hip/hip_runtime.h>

#define DEV __device__ __forceinline__

typedef __bf16 bf16x8 __attribute__((ext_vector_type(8)));
typedef float f32x4 __attribute__((ext_vector_type(4)));

union U8 { uint4 q; unsigned short u[8]; };

constexpr int BN = 4, H = 270, W = 512, HW = H * W;
constexpr int IH5 = 274, P5 = 516;   // pad-2 buffers (SIFT descriptor)
constexpr int IH3 = 272, P3 = 514;   // pad-1 buffers

DEV unsigned short f2bf(float f) {
  unsigned int u = __builtin_bit_cast(unsigned int, f);
  u = (u + 0x7FFFu + ((u >> 16) & 1u)) >> 16;
  return (unsigned short)u;
}
DEV float bf2f(unsigned short h) {
  return __builtin_bit_cast(float, (unsigned int)h << 16);
}

#define GLL16(g, l)                                                                        \
  __builtin_amdgcn_global_load_lds((const __attribute__((address_space(1))) void*)(g),     \
                                   (__attribute__((address_space(3))) void*)(l), 16, 0, 0)

// ---------------------------------------------------------------- diagnostic
__global__ void k_fill(float* __restrict__ out, int n, float v) {
  int i = blockIdx.x * 256 + threadIdx.x;
  if (i < n) out[i] = v;
}

// ---------------------------------------------------------------- halo zero (borders of padded NHWC buffer)
template <int C, int PD>
__global__ void k_halo(unsigned short* __restrict__ buf, int IHt, int pitch, int nb_) {
  int vPerRow = pitch * C / 8;
  int topBot = 2 * PD * vPerRow;
  int sideV = PD * C / 8;
  int midRows = IHt - 2 * PD;
  int perS = topBot + midRows * 2 * sideV;
  int v = blockIdx.x * 256 + threadIdx.x;
  if (v >= nb_ * perS) return;
  int s = v / perS, r = v % perS;
  size_t base = (size_t)s * IHt * pitch * C;
  size_t off;
  if (r < topBot) {
    int half = r / (PD * vPerRow);
    int rr = r % (PD * vPerRow);
    off = ((size_t)(half ? (IHt - PD) : 0) * pitch * C) + (size_t)rr * 8;
  } else {
    int r2 = r - topBot;
    int row = r2 / (2 * sideV), c2 = r2 % (2 * sideV);
    int side = c2 / sideV, cc = c2 % sideV;
    off = ((size_t)(PD + row) * pitch + (side ? (pitch - PD) : 0)) * C + (size_t)cc * 8;
  }
  *(uint4*)(buf + base + off) = uint4{0, 0, 0, 0};
}

// ---------------------------------------------------------------- SIFT stage 1
__global__ void k_sift_ang(const float* __restrict__ x, float* __restrict__ ang, int nTot) {
  int p = blockIdx.x * 256 + threadIdx.x;
  if (p >= nTot) return;
  int b = p / HW, r = p % HW, y = r / W, xx = r % W;
  const float* xb = x + (size_t)b * HW;
  float xm = xb[y * W + (xx > 0 ? xx - 1 : 0)];
  float xp = xb[y * W + (xx < W - 1 ? xx + 1 : W - 1)];
  float ym = xb[(y > 0 ? y - 1 : 0) * W + xx];
  float yp = xb[(y < H - 1 ? y + 1 : H - 1) * W + xx];
  float gx = (xp - xm) * 0.5f, gy = (yp - ym) * 0.5f;
  float mag = sqrtf(gx * gx + gy * gy + 1e-10f);
  float ori = atan2f(gy, gx + 1e-10f) + 6.2831855f;
  float o = (8.0f * ori) / 6.2831855f;
  float bo0f = floorf(o);
  float wo1 = o - bo0f;
  int b0 = ((int)bo0f) & 7;
  int b1 = (b0 + 1) & 7;
  float w0m = (1.0f - wo1) * mag, w1m = wo1 * mag;
  float v[8];
#pragma unroll
  for (int k = 0; k < 8; ++k)
    v[k] = (k == b0 ? w0m : 0.0f) + (k == b1 ? w1m : 0.0f);
  float4* o4 = (float4*)(ang + (size_t)p * 8);
  o4[0] = make_float4(v[0], v[1], v[2], v[3]);
  o4[1] = make_float4(v[4], v[5], v[6], v[7]);
}

// ---------------------------------------------------------------- SIFT stage 2
__global__ void k_sift_pool(const float* __restrict__ ang, float* __restrict__ pooled, int nTot) {
  constexpr int PH = H + 1, PW = W + 1;
  int p = blockIdx.x * 256 + threadIdx.x;
  if (p >= nTot) return;
  int b = p / (PH * PW), r = p % (PH * PW), y = r / PW, xx = r % PW;
  float4 a0 = {0, 0, 0, 0}, a1 = {0, 0, 0, 0};
  const float xc2[4] = {0.5f, 1.5f, 1.5f, 0.5f};
#pragma unroll
  for (int ky = 0; ky < 4; ++ky) {
    int yy = y - 2 + ky;
    if (yy < 0 || yy >= H) continue;
#pragma unroll
    for (int kx = 0; kx < 4; ++kx) {
      int xs = xx - 2 + kx;
      if (xs < 0 || xs >= W) continue;
      float w = xc2[ky] * xc2[kx] * 0.25f;
      const float4* s4 = (const float4*)(ang + ((size_t)(b * H + yy) * W + xs) * 8);
      float4 v0 = s4[0], v1 = s4[1];
      a0.x += w * v0.x; a0.y += w * v0.y; a0.z += w * v0.z; a0.w += w * v0.w;
      a1.x += w * v1.x; a1.y += w * v1.y; a1.z += w * v1.z; a1.w += w * v1.w;
    }
  }
  float4* o4 = (float4*)(pooled + (size_t)p * 8);
  o4[0] = a0; o4[1] = a1;
}

// ---------------------------------------------------------------- SIFT stage 3
__global__ void k_sift_desc(const float* __restrict__ pooled, unsigned short* __restrict__ spad) {
  constexpr int PH = H + 1, PW = W + 1;
  int tid = threadIdx.x;
  int wv = tid >> 6, lane = tid & 63;
  int p = blockIdx.x * 4 + wv;
  int b = p / HW, r = p % HW, yy = r / W, xx = r % W;
  int a = lane >> 3, jj = lane & 7;
  int j0 = jj * 2;
  int dy = j0 >> 2, dx = j0 & 3;
  int rr = yy + dy - 1;
  int c0 = xx + dx - 1, c1 = c0 + 1;
  bool rv = (rr >= 0 && rr <= H);
  int rc = min(max(rr, 0), H);
  const float* pb = pooled + ((size_t)(b * PH + rc) * PW) * 8 + a;
  float v0 = 0.0f, v1 = 0.0f;
  if (rv && c0 >= 0 && c0 <= W) v0 = pb[(size_t)c0 * 8];
  if (rv && c1 >= 0 && c1 <= W) v1 = pb[(size_t)c1 * 8];

  float n2 = v0 * v0 + v1 * v1;
#pragma unroll
  for (int m = 1; m < 64; m <<= 1) n2 += __shfl_xor(n2, m);
  float inv = 1.0f / fmaxf(sqrtf(n2), 1e-12f);
  v0 = fminf(v0 * inv, 0.2f);
  v1 = fminf(v1 * inv, 0.2f);
  float n2b = v0 * v0 + v1 * v1;
#pragma unroll
  for (int m = 1; m < 64; m <<= 1) n2b += __shfl_xor(n2b, m);
  inv = 1.0f / fmaxf(sqrtf(n2b), 1e-12f);
  v0 *= inv; v1 *= inv;
  float l1 = v0 + v1;
#pragma unroll
  for (int m = 1; m < 64; m <<= 1) l1 += __shfl_xor(l1, m);
  float il1 = 1.0f / fmaxf(l1, 1e-12f);
  v0 = sqrtf(v0 * il1 + 1e-10f);
  v1 = sqrtf(v1 * il1 + 1e-10f);
  unsigned int pk = (unsigned int)f2bf(v0) | ((unsigned int)f2bf(v1) << 16);
  *(unsigned int*)(spad + ((size_t)(b * IH5 + yy + 2) * P5 + xx + 2) * 128 + lane * 2) = pk;
}

// ---------------------------------------------------------------- weight prep: [t][co][ci] bf16
template <int CIN, int COUT, int KS>
__global__ void k_prep(const float* __restrict__ w, unsigned short* __restrict__ wbuf) {
  int i = blockIdx.x * 256 + threadIdx.x;
  if (i >= KS * KS * COUT * CIN) return;
  int t = i / (COUT * CIN), r2 = i % (COUT * CIN), co = r2 / CIN, e = r2 % CIN;
  wbuf[i] = f2bf(w[(co * CIN + e) * (KS * KS) + t]);
}

// ---------------------------------------------------------------- full-row MFMA conv
// Block = one output row (512 px), 4 waves x 128 px, all COUT.
// K processed in 32-ci quarter passes; slab = full padded row of one ci-quarter (33 KB).
// W quarter (COUT x 32ci) double-buffered, prefetched under MFMA.
// 384 B LDS read per MFMA (mi=8, ni=NF).
template <int CIN, int COUT, int KS, int NG, int PADOFF>
__launch_bounds__(256, 2)
__global__ void k_convr(const unsigned short* __restrict__ in, int IHt, int ipitch,
                        const unsigned short* __restrict__ wtap,
                        const float* __restrict__ bias,
                        unsigned short* __restrict__ outraw,
                        float* __restrict__ part, int nbid) {
  constexpr int SLABPX = 512 + KS - 1;
  constexpr int KQ = CIN / 32;
  constexpr int NF = COUT / 16;
  constexpr int SLAB = SLABPX * 64;     // 64 B per px (32 ci * bf16)
  constexpr int SWQ = COUT * 64;
  __shared__ __align__(16) unsigned char smem[SLAB + 2 * SWQ];
  __shared__ float red[4][16];

  int tid = threadIdx.x;
  int lane = tid & 63, wid = tid >> 6;
  int l15 = lane & 15, hi = lane >> 4;

  // bijective XCD chunk remap (m204): each XCD owns a contiguous row band
  int bid = blockIdx.x;
  int q8 = nbid >> 3, r8 = nbid & 7;
  int xcd = bid & 7;
  int by = (xcd < r8 ? xcd * (q8 + 1) : r8 * (q8 + 1) + (xcd - r8) * q8) + (bid >> 3);
  int y = by % H, b = by / H;

  f32x4 acc[8][NF] = {};

  auto stage_slab = [&](int ky, int q) {
    const char* src = (const char*)(in + ((size_t)(b * IHt + y + ky + PADOFF) * ipitch + PADOFF) * CIN + q * 32);
    for (int d = tid * 16; d < SLAB; d += 4096) {
      int px = d >> 6, qb = d & 63;
      int g = px * (CIN * 2) + (qb ^ ((px & 3) << 4));
      GLL16(src + g, smem + d);
    }
  };
  auto stage_wq = [&](int t, int q, int pbuf) {
    const char* src = (const char*)wtap + (size_t)t * (COUT * CIN * 2) + q * 64;
    unsigned char* dst = smem + SLAB + pbuf * SWQ;
    for (int d = tid * 16; d < SWQ; d += 4096) {
      int co = d >> 6, qb = d & 63;
      int g = co * (CIN * 2) + (qb ^ ((co & 3) << 4));
      GLL16(src + g, dst + d);
    }
  };

#pragma unroll 1
  for (int q = 0; q < KQ; ++q) {
    stage_slab(0, q);
    stage_wq(0, q, 0);
    __syncthreads();
#pragma unroll 1
    for (int ky = 0; ky < KS; ++ky) {
#pragma unroll
      for (int kx = 0; kx < KS; ++kx) {
        int t = ky * KS + kx;
        if (t + 1 < KS * KS) stage_wq(t + 1, q, (t + 1) & 1);  // prefetch under compute
        const unsigned char* wb = smem + SLAB + (t & 1) * SWQ;
        int koff = hi * 16;
        bf16x8 af[8];
#pragma unroll
        for (int mi = 0; mi < 8; ++mi) {
          int px = wid * 128 + mi * 16 + l15 + kx;
          af[mi] = *(const bf16x8*)(smem + px * 64 + (koff ^ ((px & 3) << 4)));
        }
#pragma unroll
        for (int ni = 0; ni < NF; ++ni) {
          int co = ni * 16 + l15;
          bf16x8 bq = *(const bf16x8*)(wb + co * 64 + (koff ^ ((co & 3) << 4)));
#pragma unroll
          for (int mi = 0; mi < 8; ++mi)
            acc[mi][ni] = __builtin_amdgcn_mfma_f32_16x16x32_bf16(af[mi], bq, acc[mi][ni], 0, 0, 0);
        }
        __syncthreads();  // W(t+1) staged; readers of buf[t&1] done -> reusable
      }
      if (ky + 1 < KS) { stage_slab(ky + 1, q); __syncthreads(); }
    }
  }

  // bias
#pragma unroll
  for (int ni = 0; ni < NF; ++ni) {
    float bv = bias[ni * 16 + l15];
#pragma unroll
    for (int mi = 0; mi < 8; ++mi)
#pragma unroll
      for (int rr = 0; rr < 4; ++rr)
        acc[mi][ni][rr] += bv;
  }
  // store raw NHWC bf16
  unsigned short* op = outraw + ((size_t)(b * H + y) * W) * COUT;
#pragma unroll
  for (int mi = 0; mi < 8; ++mi)
#pragma unroll
    for (int rr = 0; rr < 4; ++rr) {
      int px = wid * 128 + mi * 16 + hi * 4 + rr;
#pragma unroll
      for (int ni = 0; ni < NF; ++ni)
        op[(size_t)px * COUT + ni * 16 + l15] = f2bf(acc[mi][ni][rr]);
    }
  // deterministic per-row GN partials (slot = global row index)
  if constexpr (NG > 0) {
    constexpr int GPC = COUT / NG;
#pragma unroll
    for (int ni = 0; ni < NF; ++ni) {
      float s = 0.0f, q2 = 0.0f;
#pragma unroll
      for (int mi = 0; mi < 8; ++mi)
#pragma unroll
        for (int rr = 0; rr < 4; ++rr) {
          float v = acc[mi][ni][rr];
          s += v; q2 += v * v;
        }
      s += __shfl_xor(s, 16); q2 += __shfl_xor(q2, 16);
      s += __shfl_xor(s, 32); q2 += __shfl_xor(q2, 32);
#pragma unroll
      for (int m = 1; m < GPC; m <<= 1) { s += __shfl_xor(s, m); q2 += __shfl_xor(q2, m); }
      if (hi == 0 && (l15 % GPC) == 0) {
        int g = ni * (16 / GPC) + l15 / GPC;
        red[wid][g] = s;
        red[wid][NG + g] = q2;
      }
    }
    __syncthreads();
    if (tid < 2 * NG)
      part[(size_t)by * (2 * NG) + tid] =
          red[0][tid] + red[1][tid] + red[2][tid] + red[3][tid];
  }
}

// ---------------------------------------------------------------- GN finalize
template <int COUT, int NG>
__global__ void k_gn_fin(const float* __restrict__ part, int NB,
                         const float* __restrict__ gw, const float* __restrict__ gb,
                         float* __restrict__ scale, float* __restrict__ shift, float invN) {
  constexpr int GPC = COUT / NG;
  int b = blockIdx.x / NG, g = blockIdx.x % NG;
  int lane = threadIdx.x;
  float s = 0.0f, q = 0.0f;
  for (int i = lane; i < NB; i += 64) {
    const float* pp = part + (size_t)(b * NB + i) * (2 * NG);
    s += pp[g]; q += pp[NG + g];
  }
#pragma unroll
  for (int m = 1; m < 64; m <<= 1) { s += __shfl_xor(s, m); q += __shfl_xor(q, m); }
  if (lane == 0) {
    float mean = s * invN;
    float var = q * invN - mean * mean;
    float rstd = rsqrtf(var + 1e-5f);
#pragma unroll
    for (int j = 0; j < GPC; ++j) {
      int c = g * GPC + j;
      float sc = gw[c] * rstd;
      scale[b * COUT + c] = sc;
      shift[b * COUT + c] = gb[c] - mean * sc;
    }
  }
}

// ---------------------------------------------------------------- GN-apply (+ReLU, +skip)
template <int C, bool ADDSKIP>
__global__ void k_norm(const unsigned short* __restrict__ raw,
                       const unsigned short* __restrict__ skip,
                       const float* __restrict__ scale, const float* __restrict__ shift,
                       unsigned short* __restrict__ outpad) {
  int e = blockIdx.x * 256 + threadIdx.x;
  int idx = e * 8;
  int p = idx / C, c0 = idx % C;
  int b = p / HW, r = p % HW, y = r / W, xx = r % W;
  U8 v; v.q = *(const uint4*)(raw + (size_t)p * C + c0);
  U8 sk;
  if (ADDSKIP) sk.q = *(const uint4*)(skip + (size_t)p * C + c0);
  const float* sc = scale + b * C + c0;
  const float* sh = shift + b * C + c0;
  U8 o;
#pragma unroll
  for (int j = 0; j < 8; ++j) {
    float f = fmaxf(bf2f(v.u[j]) * sc[j] + sh[j], 0.0f);
    if (ADDSKIP) f += bf2f(sk.u[j]);
    o.u[j] = f2bf(f);
  }
  *(uint4*)(outpad + ((size_t)(b * IH3 + y + 1) * P3 + xx + 1) * C + c0) = o.q;
}

// ---------------------------------------------------------------- conv4 direct (16->8, 3x3)
__global__ void k_conv4(const unsigned short* __restrict__ h3pad, const float* __restrict__ w4,
                        const float* __restrict__ b4, unsigned short* __restrict__ h4raw,
                        float* __restrict__ part) {
  __shared__ float wl[1152];
  __shared__ float red[4][8];
  for (int i = threadIdx.x; i < 1152; i += 256) {
    int t = i / 128, r2 = i % 128, ci = r2 >> 3, co = r2 & 7;
    wl[i] = w4[(co * 16 + ci) * 9 + t];
  }
  __syncthreads();
  int p = blockIdx.x * 256 + threadIdx.x;
  int b = p / HW, r = p % HW, y = r / W, xx = r % W;
  float acc[8];
#pragma unroll
  for (int co = 0; co < 8; ++co) acc[co] = b4[co];
#pragma unroll
  for (int t = 0; t < 9; ++t) {
    int ky = t / 3, kx = t % 3;
    const unsigned short* ip = h3pad + ((size_t)(b * IH3 + y + ky) * P3 + (xx + kx)) * 16;
    U8 u0, u1;
    u0.q = *(const uint4*)ip;
    u1.q = *(const uint4*)(ip + 8);
#pragma unroll
    for (int ci = 0; ci < 16; ++ci) {
      float iv = bf2f(ci < 8 ? u0.u[ci] : u1.u[ci - 8]);
#pragma unroll
      for (int co = 0; co < 8; ++co)
        acc[co] += iv * wl[t * 128 + ci * 8 + co];
    }
  }
  int lane = threadIdx.x & 63, wv = threadIdx.x >> 6;
  float s[4], q[4];
#pragma unroll
  for (int g = 0; g < 4; ++g) {
    s[g] = acc[2 * g] + acc[2 * g + 1];
    q[g] = acc[2 * g] * acc[2 * g] + acc[2 * g + 1] * acc[2 * g + 1];
  }
#pragma unroll
  for (int m = 1; m < 64; m <<= 1) {
#pragma unroll
    for (int g = 0; g < 4; ++g) { s[g] += __shfl_xor(s[g], m); q[g] += __shfl_xor(q[g], m); }
  }
  if (lane == 0) {
#pragma unroll
    for (int g = 0; g < 4; ++g) { red[wv][g] = s[g]; red[wv][4 + g] = q[g]; }
  }
  __syncthreads();
  if (threadIdx.x < 8)
    part[(size_t)blockIdx.x * 8 + threadIdx.x] =
        red[0][threadIdx.x] + red[1][threadIdx.x] + red[2][threadIdx.x] + red[3][threadIdx.x];
  U8 o;
#pragma unroll
  for (int co = 0; co < 8; ++co) o.u[co] = f2bf(acc[co]);
  *(uint4*)(h4raw + (size_t)p * 8) = o.q;
}

// ---------------------------------------------------------------- norm4 + skip2 (1x1 32->8)
__global__ void k_norm4(const unsigned short* __restrict__ h4raw, const unsigned short* __restrict__ blkpad,
                        const float* __restrict__ scale, const float* __restrict__ shift,
                        const float* __restrict__ sw2, const float* __restrict__ sb2,
                        unsigned short* __restrict__ blk2pad) {
  __shared__ float wl[256];
  {
    int i = threadIdx.x;
    int ci = i >> 3, co = i & 7;
    wl[i] = sw2[co * 32 + ci];
  }
  __syncthreads();
  int p = blockIdx.x * 256 + threadIdx.x;
  int b = p / HW, r = p % HW, y = r / W, xx = r % W;
  float acc[8];
#pragma unroll
  for (int co = 0; co < 8; ++co) acc[co] = sb2[co];
  size_t cbase = ((size_t)(b * IH3 + y + 1) * P3 + (xx + 1));
  const unsigned short* bp = blkpad + cbase * 32;
#pragma unroll
  for (int half = 0; half < 4; ++half) {
    U8 u; u.q = *(const uint4*)(bp + half * 8);
#pragma unroll
    for (int j = 0; j < 8; ++j) {
      float iv = bf2f(u.u[j]);
      int ci = half * 8 + j;
#pragma unroll
      for (int co = 0; co < 8; ++co) acc[co] += iv * wl[ci * 8 + co];
    }
  }
  U8 hv; hv.q = *(const uint4*)(h4raw + (size_t)p * 8);
  U8 o;
#pragma unroll
  for (int co = 0; co < 8; ++co) {
    float f = fmaxf(bf2f(hv.u[co]) * scale[b * 8 + co] + shift[b * 8 + co], 0.0f) + acc[co];
    o.u[co] = f2bf(f);
  }
  *(uint4*)(blk2pad + cbase * 8) = o.q;
}

// ---------------------------------------------------------------- conv5 direct (8->2, 3x3)
__global__ void k_conv5(const unsigned short* __restrict__ blk2pad, const float* __restrict__ w5,
                        const float* __restrict__ b5, float* __restrict__ h5) {
  __shared__ float wl[144];
  if (threadIdx.x < 144) {
    int i = threadIdx.x;
    int t = i / 16, r2 = i % 16, ci = r2 >> 1, co = r2 & 1;
    wl[i] = w5[(co * 8 + ci) * 9 + t];
  }
  __syncthreads();
  int p = blockIdx.x * 256 + threadIdx.x;
  int b = p / HW, r = p % HW, y = r / W, xx = r % W;
  float a0 = b5[0], a1 = b5[1];
#pragma unroll
  for (int t = 0; t < 9; ++t) {
    int ky = t / 3, kx = t % 3;
    const unsigned short* ip = blk2pad + ((size_t)(b * IH3 + y + ky) * P3 + (xx + kx)) * 8;
    U8 u; u.q = *(const uint4*)ip;
#pragma unroll
    for (int ci = 0; ci < 8; ++ci) {
      float iv = bf2f(u.u[ci]);
      a0 += iv * wl[t * 16 + ci * 2];
      a1 += iv * wl[t * 16 + ci * 2 + 1];
    }
  }
  h5[(size_t)p * 2] = a0;
  h5[(size_t)p * 2 + 1] = a1;
}

// ---------------------------------------------------------------- joint bilateral + tanh + scale
__global__ void k_bilateral(const float* __restrict__ h5, const float* __restrict__ x,
                            float* __restrict__ out, int nTot) {
  int p = blockIdx.x * 256 + threadIdx.x;
  if (p >= nTot) return;
  int b = p / HW, r = p % HW, y = r / W, xx = r % W;
  const float* xb = x + (size_t)b * HW;
  float xc = xb[r];
  float e1 = expf(-1.0f / 4.5f), e0 = expf(-4.0f / 4.5f);
  float gs = 1.0f + 2.0f * e1 + 2.0f * e0;
  float g[5] = {e0 / gs, e1 / gs, 1.0f / gs, e1 / gs, e0 / gs};
  float n0 = 0.0f, n1 = 0.0f, den = 0.0f;
#pragma unroll
  for (int dy = 0; dy < 5; ++dy) {
    int yn = y + dy - 2;
    yn = yn < 0 ? -yn : (yn >= H ? 2 * H - 2 - yn : yn);
#pragma unroll
    for (int dx = 0; dx < 5; ++dx) {
      int xn = xx + dx - 2;
      xn = xn < 0 ? -xn : (xn >= W ? 2 * W - 2 - xn : xn);
      float xv = xb[yn * W + xn];
      float d = xv - xc;
      float wgt = g[dy] * g[dx] * expf(-200.0f * d * d);
      den += wgt;
      const float* hp = h5 + ((size_t)(b * HW) + yn * W + xn) * 2;
      n0 += wgt * hp[0];
      n1 += wgt * hp[1];
    }
  }
  float o0 = tanhf(n0 / den) * 0.436f;
  float o1 = tanhf(n1 / den) * 0.615f;
  out[(size_t)(b * 2) * HW + r] = o0;
  out[(size_t)(b * 2 + 1) * HW + r] = o1;
}

// ---------------------------------------------------------------- host
extern "C" void kernel_launch(void* const* d_in, const int* in_sizes, int n_in,
                              void* d_out, int out_size, void* d_ws, size_t ws_size,
                              hipStream_t stream) {
  (void)in_sizes; (void)n_in; (void)out_size;
  const float* x   = (const float*)d_in[0];
  const float* w1  = (const float*)d_in[1];
  const float* b1  = (const float*)d_in[2];
  const float* g1w = (const float*)d_in[3];
  const float* g1b = (const float*)d_in[4];
  const float* w2  = (const float*)d_in[5];
  const float* b2  = (const float*)d_in[6];
  const float* g2w = (const float*)d_in[7];
  const float* g2b = (const float*)d_in[8];
  const float* w3  = (const float*)d_in[9];
  const float* b3  = (const float*)d_in[10];
  const float* g3w = (const float*)d_in[11];
  const float* g3b = (const float*)d_in[12];
  const float* w4  = (const float*)d_in[13];
  const float* b4  = (const float*)d_in[14];
  const float* g4w = (const float*)d_in[15];
  const float* g4b = (const float*)d_in[16];
  const float* w5  = (const float*)d_in[17];
  const float* b5  = (const float*)d_in[18];
  const float* sw1 = (const float*)d_in[19];
  const float* sb1 = (const float*)d_in[20];
  const float* sw2 = (const float*)d_in[21];
  const float* sb2 = (const float*)d_in[22];
  float* out = (float*)d_out;
  char* ws = (char*)d_ws;

  auto AL = [](size_t v) { return (v + 255) & ~(size_t)255; };
  const size_t sSPAD  = (size_t)IH5 * P5 * 128 * 2;
  const size_t sANG   = (size_t)HW * 8 * 4;
  const size_t sH1RAW = (size_t)HW * 64 * 2;
  const size_t sH1PAD = (size_t)IH3 * P3 * 64 * 2;
  const size_t sH2RAW = (size_t)HW * 32 * 2;
  const size_t sBLKP  = (size_t)IH3 * P3 * 32 * 2;
  const size_t sH3RAW = (size_t)HW * 16 * 2;
  const size_t sH3PAD = (size_t)IH3 * P3 * 16 * 2;
  const size_t sH4RAW = (size_t)HW * 8 * 2;
  const size_t sBLK2  = (size_t)IH3 * P3 * 8 * 2;

  int nb = 0;
  size_t offB = 0, offH1PAD = 0, offSmall = 0;
  const size_t smallFixed = AL(1024 * 1024) + AL((size_t)4 * 1080 * 16 * 4) + 8 * 4096;
  for (int cand = 4; cand >= 1; cand >>= 1) {
    size_t oB   = AL((size_t)cand * sSPAD);
    size_t oH1P = AL(oB + (size_t)cand * sH1RAW);
    size_t oS   = AL(oH1P + (size_t)cand * sH1PAD);
    size_t need = oS + smallFixed + AL((size_t)cand * sH2RAW);
    if (ws_size >= need) { nb = cand; offB = oB; offH1PAD = oH1P; offSmall = oS; break; }
  }
  if (nb == 0) {
    k_fill<<<(BN * 2 * HW + 255) / 256, 256, 0, stream>>>(out, BN * 2 * HW, 123.0f);
    return;
  }

  size_t oWB1  = offSmall;
  size_t oWB2  = AL(oWB1 + 25 * 64 * 128 * 2);
  size_t oWB3  = AL(oWB2 + 9 * 32 * 64 * 2);
  size_t oWBS  = AL(oWB3 + 9 * 16 * 32 * 2);
  size_t oPART = AL(oWBS + 32 * 128 * 2);
  size_t oSC1  = AL(oPART + (size_t)4 * 1080 * 16 * 4);
  size_t oSC2  = oSC1 + 4096, oSC3 = oSC2 + 4096, oSC4 = oSC3 + 4096;
  size_t oSK1  = oSC4 + 4096;

  unsigned short* wb1  = (unsigned short*)(ws + oWB1);
  unsigned short* wb2  = (unsigned short*)(ws + oWB2);
  unsigned short* wb3  = (unsigned short*)(ws + oWB3);
  unsigned short* wbs1 = (unsigned short*)(ws + oWBS);
  float* part = (float*)(ws + oPART);
  float* sc1 = (float*)(ws + oSC1); float* sh1 = sc1 + nb * 64;
  float* sc2 = (float*)(ws + oSC2); float* sh2 = sc2 + nb * 32;
  float* sc3 = (float*)(ws + oSC3); float* sh3 = sc3 + nb * 16;
  float* sc4 = (float*)(ws + oSC4); float* sh4 = sc4 + nb * 8;
  unsigned short* sk1 = (unsigned short*)(ws + oSK1);

  k_prep<128, 64, 5><<<800, 256, 0, stream>>>(w1, wb1);
  k_prep<64, 32, 3><<<72, 256, 0, stream>>>(w2, wb2);
  k_prep<32, 16, 3><<<18, 256, 0, stream>>>(w3, wb3);
  k_prep<128, 32, 1><<<16, 256, 0, stream>>>(sw1, wbs1);

  size_t t0 = AL((size_t)nb * sBLKP);
  size_t t1 = AL(t0 + (size_t)nb * sH3RAW);
  size_t t2 = AL(t1 + (size_t)nb * sH3PAD);
  size_t t3 = AL(t2 + (size_t)nb * sH4RAW);
  size_t t4 = AL(t3 + (size_t)nb * sBLK2);

  for (int b0 = 0; b0 < BN; b0 += nb) {
    const float* x_c = x + (size_t)b0 * HW;
    float* out_c = out + (size_t)b0 * 2 * HW;
    unsigned short* spad   = (unsigned short*)(ws);
    float*          ang    = (float*)(ws + offB);
    float*          pooled = (float*)(ws + AL(offB + (size_t)nb * sANG));
    unsigned short* h1raw  = (unsigned short*)(ws + offB);
    unsigned short* h1pad  = (unsigned short*)(ws + offH1PAD);
    unsigned short* h2raw  = (unsigned short*)(ws + offB);
    unsigned short* blkpad = (unsigned short*)(ws);
    unsigned short* h3raw  = (unsigned short*)(ws + t0);
    unsigned short* h3pad  = (unsigned short*)(ws + t1);
    unsigned short* h4raw  = (unsigned short*)(ws + t2);
    unsigned short* blk2   = (unsigned short*)(ws + t3);
    float*          h5     = (float*)(ws + t4);
    int nHW = nb * HW;
    int nbid = nb * H;

    // halo-only zeroing (interiors are fully overwritten each chunk)
    k_halo<128, 2><<<(nb * 50304 + 255) / 256, 256, 0, stream>>>(spad, IH5, P5, nb);
    k_halo<64, 1><<<(nb * 12544 + 255) / 256, 256, 0, stream>>>(h1pad, IH3, P3, nb);

    k_sift_ang<<<nb * 540, 256, 0, stream>>>(x_c, ang, nHW);
    int nPP = nb * (H + 1) * (W + 1);
    k_sift_pool<<<(nPP + 255) / 256, 256, 0, stream>>>(ang, pooled, nPP);
    k_sift_desc<<<nHW / 4, 256, 0, stream>>>(pooled, spad);

    // conv1 (5x5, 128->64)
    k_convr<128, 64, 5, 8, 0><<<nbid, 256, 0, stream>>>(spad, IH5, P5, wb1, b1, h1raw, part, nbid);
    k_gn_fin<64, 8><<<nb * 8, 64, 0, stream>>>(part, H, g1w, g1b, sc1, sh1, 1.0f / (8.0f * HW));
    k_norm<64, false><<<nb * 4320, 256, 0, stream>>>(h1raw, nullptr, sc1, sh1, h1pad);

    // conv2 (3x3, 64->32)
    k_convr<64, 32, 3, 8, 0><<<nbid, 256, 0, stream>>>(h1pad, IH3, P3, wb2, b2, h2raw, part, nbid);
    k_gn_fin<32, 8><<<nb * 8, 64, 0, stream>>>(part, H, g2w, g2b, sc2, sh2, 1.0f / (4.0f * HW));
    // skip1 (1x1, 128->32) on spad
    k_convr<128, 32, 1, 0, 2><<<nbid, 256, 0, stream>>>(spad, IH5, P5, wbs1, sb1, sk1, nullptr, nbid);

    // spad dead; its region hosts blkpad + tail buffers
    k_halo<32, 1><<<(nb * 6272 + 255) / 256, 256, 0, stream>>>(blkpad, IH3, P3, nb);
    k_halo<16, 1><<<(nb * 3136 + 255) / 256, 256, 0, stream>>>(h3pad, IH3, P3, nb);
    k_halo<8, 1><<<(nb * 1568 + 255) / 256, 256, 0, stream>>>(blk2, IH3, P3, nb);

    k_norm<32, true><<<nb * 2160, 256, 0, stream>>>(h2raw, sk1, sc2, sh2, blkpad);

    // conv3 (3x3, 32->16)
    k_convr<32, 16, 3, 4, 0><<<nbid, 256, 0, stream>>>(blkpad, IH3, P3, wb3, b3, h3raw, part, nbid);
    k_gn_fin<16, 4><<<nb * 4, 64, 0, stream>>>(part, H, g3w, g3b, sc3, sh3, 1.0f / (4.0f * HW));
    k_norm<16, false><<<nb * 1080, 256, 0, stream>>>(h3raw, nullptr, sc3, sh3, h3pad);

    k_conv4<<<nb * 540, 256, 0, stream>>>(h3pad, w4, b4, h4raw, part);
    k_gn_fin<8, 4><<<nb * 4, 64, 0, stream>>>(part, 540, g4w, g4b, sc4, sh4, 1.0f / (2.0f * HW));
    k_norm4<<<nb * 540, 256, 0, stream>>>(h4raw, blkpad, sc4, sh4, sw2, sb2, blk2);

    k_conv5<<<nb * 540, 256, 0, stream>>>(blk2, w5, b5, h5);
    k_bilateral<<<nb * 540, 256, 0, stream>>>(h5, x_c, out_c, nHW);
  }
}

// Round 6
// 807.157 us; speedup vs baseline: 1.0494x; 1.0494x over previous
//
#include <hip/hip_runtime.h>

#define DEV __device__ __forceinline__

typedef __bf16 bf16x8 __attribute__((ext_vector_type(8)));
typedef float f32x4 __attribute__((ext_vector_type(4)));

union U8 { uint4 q; unsigned short u[8]; };

constexpr int BN = 4, H = 270, W = 512, HW = H * W;
constexpr int IH5 = 274, P5 = 516;   // pad-2 buffers (SIFT descriptor)
constexpr int IH3 = 272, P3 = 514;   // pad-1 buffers

DEV unsigned short f2bf(float f) {
  unsigned int u = __builtin_bit_cast(unsigned int, f);
  u = (u + 0x7FFFu + ((u >> 16) & 1u)) >> 16;
  return (unsigned short)u;
}
DEV float bf2f(unsigned short h) {
  return __builtin_bit_cast(float, (unsigned int)h << 16);
}

#define GLL16(g, l)                                                                        \
  __builtin_amdgcn_global_load_lds((const __attribute__((address_space(1))) void*)(g),     \
                                   (__attribute__((address_space(3))) void*)(l), 16, 0, 0)

// swizzle: XOR 16B-slot with ((row>>1)&3) -> 2-way (free) bank aliasing on stride-64B reads
DEV int swz(int row) { return ((row >> 1) & 3) << 4; }

// ---------------------------------------------------------------- diagnostic
__global__ void k_fill(float* __restrict__ out, int n, float v) {
  int i = blockIdx.x * 256 + threadIdx.x;
  if (i < n) out[i] = v;
}

// ---------------------------------------------------------------- halo zero
template <int C, int PD>
__global__ void k_halo(unsigned short* __restrict__ buf, int IHt, int pitch, int nb_) {
  int vPerRow = pitch * C / 8;
  int topBot = 2 * PD * vPerRow;
  int sideV = PD * C / 8;
  int midRows = IHt - 2 * PD;
  int perS = topBot + midRows * 2 * sideV;
  int v = blockIdx.x * 256 + threadIdx.x;
  if (v >= nb_ * perS) return;
  int s = v / perS, r = v % perS;
  size_t base = (size_t)s * IHt * pitch * C;
  size_t off;
  if (r < topBot) {
    int half = r / (PD * vPerRow);
    int rr = r % (PD * vPerRow);
    off = ((size_t)(half ? (IHt - PD) : 0) * pitch * C) + (size_t)rr * 8;
  } else {
    int r2 = r - topBot;
    int row = r2 / (2 * sideV), c2 = r2 % (2 * sideV);
    int side = c2 / sideV, cc = c2 % sideV;
    off = ((size_t)(PD + row) * pitch + (side ? (pitch - PD) : 0)) * C + (size_t)cc * 8;
  }
  *(uint4*)(buf + base + off) = uint4{0, 0, 0, 0};
}

// ---------------------------------------------------------------- SIFT stage 1
__global__ void k_sift_ang(const float* __restrict__ x, float* __restrict__ ang, int nTot) {
  int p = blockIdx.x * 256 + threadIdx.x;
  if (p >= nTot) return;
  int b = p / HW, r = p % HW, y = r / W, xx = r % W;
  const float* xb = x + (size_t)b * HW;
  float xm = xb[y * W + (xx > 0 ? xx - 1 : 0)];
  float xp = xb[y * W + (xx < W - 1 ? xx + 1 : W - 1)];
  float ym = xb[(y > 0 ? y - 1 : 0) * W + xx];
  float yp = xb[(y < H - 1 ? y + 1 : H - 1) * W + xx];
  float gx = (xp - xm) * 0.5f, gy = (yp - ym) * 0.5f;
  float mag = sqrtf(gx * gx + gy * gy + 1e-10f);
  float ori = atan2f(gy, gx + 1e-10f) + 6.2831855f;
  float o = (8.0f * ori) / 6.2831855f;
  float bo0f = floorf(o);
  float wo1 = o - bo0f;
  int b0 = ((int)bo0f) & 7;
  int b1 = (b0 + 1) & 7;
  float w0m = (1.0f - wo1) * mag, w1m = wo1 * mag;
  float v[8];
#pragma unroll
  for (int k = 0; k < 8; ++k)
    v[k] = (k == b0 ? w0m : 0.0f) + (k == b1 ? w1m : 0.0f);
  float4* o4 = (float4*)(ang + (size_t)p * 8);
  o4[0] = make_float4(v[0], v[1], v[2], v[3]);
  o4[1] = make_float4(v[4], v[5], v[6], v[7]);
}

// ---------------------------------------------------------------- SIFT stage 2
__global__ void k_sift_pool(const float* __restrict__ ang, float* __restrict__ pooled, int nTot) {
  constexpr int PH = H + 1, PW = W + 1;
  int p = blockIdx.x * 256 + threadIdx.x;
  if (p >= nTot) return;
  int b = p / (PH * PW), r = p % (PH * PW), y = r / PW, xx = r % PW;
  float4 a0 = {0, 0, 0, 0}, a1 = {0, 0, 0, 0};
  const float xc2[4] = {0.5f, 1.5f, 1.5f, 0.5f};
#pragma unroll
  for (int ky = 0; ky < 4; ++ky) {
    int yy = y - 2 + ky;
    if (yy < 0 || yy >= H) continue;
#pragma unroll
    for (int kx = 0; kx < 4; ++kx) {
      int xs = xx - 2 + kx;
      if (xs < 0 || xs >= W) continue;
      float w = xc2[ky] * xc2[kx] * 0.25f;
      const float4* s4 = (const float4*)(ang + ((size_t)(b * H + yy) * W + xs) * 8);
      float4 v0 = s4[0], v1 = s4[1];
      a0.x += w * v0.x; a0.y += w * v0.y; a0.z += w * v0.z; a0.w += w * v0.w;
      a1.x += w * v1.x; a1.y += w * v1.y; a1.z += w * v1.z; a1.w += w * v1.w;
    }
  }
  float4* o4 = (float4*)(pooled + (size_t)p * 8);
  o4[0] = a0; o4[1] = a1;
}

// ---------------------------------------------------------------- SIFT stage 3
__global__ void k_sift_desc(const float* __restrict__ pooled, unsigned short* __restrict__ spad) {
  constexpr int PH = H + 1, PW = W + 1;
  int tid = threadIdx.x;
  int wv = tid >> 6, lane = tid & 63;
  int p = blockIdx.x * 4 + wv;
  int b = p / HW, r = p % HW, yy = r / W, xx = r % W;
  int a = lane >> 3, jj = lane & 7;
  int j0 = jj * 2;
  int dy = j0 >> 2, dx = j0 & 3;
  int rr = yy + dy - 1;
  int c0 = xx + dx - 1, c1 = c0 + 1;
  bool rv = (rr >= 0 && rr <= H);
  int rc = min(max(rr, 0), H);
  const float* pb = pooled + ((size_t)(b * PH + rc) * PW) * 8 + a;
  float v0 = 0.0f, v1 = 0.0f;
  if (rv && c0 >= 0 && c0 <= W) v0 = pb[(size_t)c0 * 8];
  if (rv && c1 >= 0 && c1 <= W) v1 = pb[(size_t)c1 * 8];

  float n2 = v0 * v0 + v1 * v1;
#pragma unroll
  for (int m = 1; m < 64; m <<= 1) n2 += __shfl_xor(n2, m);
  float inv = 1.0f / fmaxf(sqrtf(n2), 1e-12f);
  v0 = fminf(v0 * inv, 0.2f);
  v1 = fminf(v1 * inv, 0.2f);
  float n2b = v0 * v0 + v1 * v1;
#pragma unroll
  for (int m = 1; m < 64; m <<= 1) n2b += __shfl_xor(n2b, m);
  inv = 1.0f / fmaxf(sqrtf(n2b), 1e-12f);
  v0 *= inv; v1 *= inv;
  float l1 = v0 + v1;
#pragma unroll
  for (int m = 1; m < 64; m <<= 1) l1 += __shfl_xor(l1, m);
  float il1 = 1.0f / fmaxf(l1, 1e-12f);
  v0 = sqrtf(v0 * il1 + 1e-10f);
  v1 = sqrtf(v1 * il1 + 1e-10f);
  unsigned int pk = (unsigned int)f2bf(v0) | ((unsigned int)f2bf(v1) << 16);
  *(unsigned int*)(spad + ((size_t)(b * IH5 + yy + 2) * P5 + xx + 2) * 128 + lane * 2) = pk;
}

// ---------------------------------------------------------------- weight prep: [t][co][ci] bf16
template <int CIN, int COUT, int KS>
__global__ void k_prep(const float* __restrict__ w, unsigned short* __restrict__ wbuf) {
  int i = blockIdx.x * 256 + threadIdx.x;
  if (i >= KS * KS * COUT * CIN) return;
  int t = i / (COUT * CIN), r2 = i % (COUT * CIN), co = r2 / CIN, e = r2 % CIN;
  wbuf[i] = f2bf(w[(co * CIN + e) * (KS * KS) + t]);
}

// ---------------------------------------------------------------- full-row MFMA conv
// Block = one output row (512 px), 4 waves x 128 px, all COUT.
// Unit of work between barriers = one (ci-quarter, ky): slab row + full W ky-row,
// both double-buffered, staged via global_load_lds with pre-swizzled source.
// One barrier per unit; GLL latency hides under KS*32 MFMAs.
template <int CIN, int COUT, int KS, int NG, int PADOFF, int MINB>
__launch_bounds__(256, MINB)
__global__ void k_convr(const unsigned short* __restrict__ in, int IHt, int ipitch,
                        const unsigned short* __restrict__ wtap,
                        const float* __restrict__ bias,
                        unsigned short* __restrict__ outraw,
                        float* __restrict__ part, int nbid) {
  constexpr int SLABPX = 512 + KS - 1;
  constexpr int KQ = CIN / 32;
  constexpr int NF = COUT / 16;
  constexpr int SLAB = SLABPX * 64;     // 64 B per px (32 ci * bf16)
  constexpr int SWQ = COUT * 64;        // one tap's ci-quarter of W
  constexpr int SWROW = KS * SWQ;       // full ky-row of W
  __shared__ __align__(16) unsigned char slabB[2][SLAB];
  __shared__ __align__(16) unsigned char wrowB[2][SWROW];
  __shared__ float red[4][16];

  int tid = threadIdx.x;
  int lane = tid & 63, wid = tid >> 6;
  int l15 = lane & 15, hi = lane >> 4;

  // bijective XCD chunk remap (m204)
  int bid = blockIdx.x;
  int q8 = nbid >> 3, r8 = nbid & 7;
  int xcd = bid & 7;
  int by = (xcd < r8 ? xcd * (q8 + 1) : r8 * (q8 + 1) + (xcd - r8) * q8) + (bid >> 3);
  int y = by % H, b = by / H;

  f32x4 acc[8][NF] = {};

  auto stage = [&](int it, int pbuf) {
    int q = it / KS, ky = it % KS;
    const char* src = (const char*)(in + ((size_t)(b * IHt + y + ky + PADOFF) * ipitch + PADOFF) * CIN + q * 32);
    for (int d = tid * 16; d < SLAB; d += 4096) {
      int px = d >> 6, qb = d & 63;
      GLL16(src + px * (CIN * 2) + (qb ^ swz(px)), slabB[pbuf] + d);
    }
    const char* wsrc = (const char*)wtap + (size_t)(ky * KS) * (COUT * CIN * 2) + q * 64;
    for (int d = tid * 16; d < SWROW; d += 4096) {
      int kx = d / SWQ, rem = d % SWQ;
      int co = rem >> 6, qb = rem & 63;
      GLL16(wsrc + (size_t)kx * (COUT * CIN * 2) + co * (CIN * 2) + (qb ^ swz(co)), wrowB[pbuf] + d);
    }
  };

  stage(0, 0);
  __syncthreads();   // compiler drains vmcnt before barrier -> staged data visible

#pragma unroll 1
  for (int it = 0; it < KQ * KS; ++it) {
    int cur = it & 1;
    if (it + 1 < KQ * KS) stage(it + 1, cur ^ 1);   // overlap with compute below
    const unsigned char* sl = slabB[cur];
    const unsigned char* wr = wrowB[cur];
    int koff = hi * 16;
#pragma unroll
    for (int kx = 0; kx < KS; ++kx) {
      bf16x8 af[8];
#pragma unroll
      for (int mi = 0; mi < 8; ++mi) {
        int px = wid * 128 + mi * 16 + l15 + kx;
        af[mi] = *(const bf16x8*)(sl + px * 64 + (koff ^ swz(px)));
      }
#pragma unroll
      for (int ni = 0; ni < NF; ++ni) {
        int co = ni * 16 + l15;
        bf16x8 bq = *(const bf16x8*)(wr + kx * SWQ + co * 64 + (koff ^ swz(co)));
#pragma unroll
        for (int mi = 0; mi < 8; ++mi)
          acc[mi][ni] = __builtin_amdgcn_mfma_f32_16x16x32_bf16(af[mi], bq, acc[mi][ni], 0, 0, 0);
      }
    }
    __syncthreads();   // my reads of buf[cur] done; stage(it+1) drained -> next iter safe
  }

  // bias
#pragma unroll
  for (int ni = 0; ni < NF; ++ni) {
    float bv = bias[ni * 16 + l15];
#pragma unroll
    for (int mi = 0; mi < 8; ++mi)
#pragma unroll
      for (int rr = 0; rr < 4; ++rr)
        acc[mi][ni][rr] += bv;
  }
  // store raw NHWC bf16
  unsigned short* op = outraw + ((size_t)(b * H + y) * W) * COUT;
#pragma unroll
  for (int mi = 0; mi < 8; ++mi)
#pragma unroll
    for (int rr = 0; rr < 4; ++rr) {
      int px = wid * 128 + mi * 16 + hi * 4 + rr;
#pragma unroll
      for (int ni = 0; ni < NF; ++ni)
        op[(size_t)px * COUT + ni * 16 + l15] = f2bf(acc[mi][ni][rr]);
    }
  // deterministic per-row GN partials (slot = global row index)
  if constexpr (NG > 0) {
    constexpr int GPC = COUT / NG;
#pragma unroll
    for (int ni = 0; ni < NF; ++ni) {
      float s = 0.0f, q2 = 0.0f;
#pragma unroll
      for (int mi = 0; mi < 8; ++mi)
#pragma unroll
        for (int rr = 0; rr < 4; ++rr) {
          float v = acc[mi][ni][rr];
          s += v; q2 += v * v;
        }
      s += __shfl_xor(s, 16); q2 += __shfl_xor(q2, 16);
      s += __shfl_xor(s, 32); q2 += __shfl_xor(q2, 32);
#pragma unroll
      for (int m = 1; m < GPC; m <<= 1) { s += __shfl_xor(s, m); q2 += __shfl_xor(q2, m); }
      if (hi == 0 && (l15 % GPC) == 0) {
        int g = ni * (16 / GPC) + l15 / GPC;
        red[wid][g] = s;
        red[wid][NG + g] = q2;
      }
    }
    __syncthreads();
    if (tid < 2 * NG)
      part[(size_t)by * (2 * NG) + tid] =
          red[0][tid] + red[1][tid] + red[2][tid] + red[3][tid];
  }
}

// ---------------------------------------------------------------- GN finalize
template <int COUT, int NG>
__global__ void k_gn_fin(const float* __restrict__ part, int NB,
                         const float* __restrict__ gw, const float* __restrict__ gb,
                         float* __restrict__ scale, float* __restrict__ shift, float invN) {
  constexpr int GPC = COUT / NG;
  int b = blockIdx.x / NG, g = blockIdx.x % NG;
  int lane = threadIdx.x;
  float s = 0.0f, q = 0.0f;
  for (int i = lane; i < NB; i += 64) {
    const float* pp = part + (size_t)(b * NB + i) * (2 * NG);
    s += pp[g]; q += pp[NG + g];
  }
#pragma unroll
  for (int m = 1; m < 64; m <<= 1) { s += __shfl_xor(s, m); q += __shfl_xor(q, m); }
  if (lane == 0) {
    float mean = s * invN;
    float var = q * invN - mean * mean;
    float rstd = rsqrtf(var + 1e-5f);
#pragma unroll
    for (int j = 0; j < GPC; ++j) {
      int c = g * GPC + j;
      float sc = gw[c] * rstd;
      scale[b * COUT + c] = sc;
      shift[b * COUT + c] = gb[c] - mean * sc;
    }
  }
}

// ---------------------------------------------------------------- GN-apply (+ReLU, +skip)
template <int C, bool ADDSKIP>
__global__ void k_norm(const unsigned short* __restrict__ raw,
                       const unsigned short* __restrict__ skip,
                       const float* __restrict__ scale, const float* __restrict__ shift,
                       unsigned short* __restrict__ outpad) {
  int e = blockIdx.x * 256 + threadIdx.x;
  int idx = e * 8;
  int p = idx / C, c0 = idx % C;
  int b = p / HW, r = p % HW, y = r / W, xx = r % W;
  U8 v; v.q = *(const uint4*)(raw + (size_t)p * C + c0);
  U8 sk;
  if (ADDSKIP) sk.q = *(const uint4*)(skip + (size_t)p * C + c0);
  const float* sc = scale + b * C + c0;
  const float* sh = shift + b * C + c0;
  U8 o;
#pragma unroll
  for (int j = 0; j < 8; ++j) {
    float f = fmaxf(bf2f(v.u[j]) * sc[j] + sh[j], 0.0f);
    if (ADDSKIP) f += bf2f(sk.u[j]);
    o.u[j] = f2bf(f);
  }
  *(uint4*)(outpad + ((size_t)(b * IH3 + y + 1) * P3 + xx + 1) * C + c0) = o.q;
}

// ---------------------------------------------------------------- conv4 direct (16->8, 3x3)
__global__ void k_conv4(const unsigned short* __restrict__ h3pad, const float* __restrict__ w4,
                        const float* __restrict__ b4, unsigned short* __restrict__ h4raw,
                        float* __restrict__ part) {
  __shared__ float wl[1152];
  __shared__ float red[4][8];
  for (int i = threadIdx.x; i < 1152; i += 256) {
    int t = i / 128, r2 = i % 128, ci = r2 >> 3, co = r2 & 7;
    wl[i] = w4[(co * 16 + ci) * 9 + t];
  }
  __syncthreads();
  int p = blockIdx.x * 256 + threadIdx.x;
  int b = p / HW, r = p % HW, y = r / W, xx = r % W;
  float acc[8];
#pragma unroll
  for (int co = 0; co < 8; ++co) acc[co] = b4[co];
#pragma unroll
  for (int t = 0; t < 9; ++t) {
    int ky = t / 3, kx = t % 3;
    const unsigned short* ip = h3pad + ((size_t)(b * IH3 + y + ky) * P3 + (xx + kx)) * 16;
    U8 u0, u1;
    u0.q = *(const uint4*)ip;
    u1.q = *(const uint4*)(ip + 8);
#pragma unroll
    for (int ci = 0; ci < 16; ++ci) {
      float iv = bf2f(ci < 8 ? u0.u[ci] : u1.u[ci - 8]);
#pragma unroll
      for (int co = 0; co < 8; ++co)
        acc[co] += iv * wl[t * 128 + ci * 8 + co];
    }
  }
  int lane = threadIdx.x & 63, wv = threadIdx.x >> 6;
  float s[4], q[4];
#pragma unroll
  for (int g = 0; g < 4; ++g) {
    s[g] = acc[2 * g] + acc[2 * g + 1];
    q[g] = acc[2 * g] * acc[2 * g] + acc[2 * g + 1] * acc[2 * g + 1];
  }
#pragma unroll
  for (int m = 1; m < 64; m <<= 1) {
#pragma unroll
    for (int g = 0; g < 4; ++g) { s[g] += __shfl_xor(s[g], m); q[g] += __shfl_xor(q[g], m); }
  }
  if (lane == 0) {
#pragma unroll
    for (int g = 0; g < 4; ++g) { red[wv][g] = s[g]; red[wv][4 + g] = q[g]; }
  }
  __syncthreads();
  if (threadIdx.x < 8)
    part[(size_t)blockIdx.x * 8 + threadIdx.x] =
        red[0][threadIdx.x] + red[1][threadIdx.x] + red[2][threadIdx.x] + red[3][threadIdx.x];
  U8 o;
#pragma unroll
  for (int co = 0; co < 8; ++co) o.u[co] = f2bf(acc[co]);
  *(uint4*)(h4raw + (size_t)p * 8) = o.q;
}

// ---------------------------------------------------------------- norm4 + skip2 (1x1 32->8)
__global__ void k_norm4(const unsigned short* __restrict__ h4raw, const unsigned short* __restrict__ blkpad,
                        const float* __restrict__ scale, const float* __restrict__ shift,
                        const float* __restrict__ sw2, const float* __restrict__ sb2,
                        unsigned short* __restrict__ blk2pad) {
  __shared__ float wl[256];
  {
    int i = threadIdx.x;
    int ci = i >> 3, co = i & 7;
    wl[i] = sw2[co * 32 + ci];
  }
  __syncthreads();
  int p = blockIdx.x * 256 + threadIdx.x;
  int b = p / HW, r = p % HW, y = r / W, xx = r % W;
  float acc[8];
#pragma unroll
  for (int co = 0; co < 8; ++co) acc[co] = sb2[co];
  size_t cbase = ((size_t)(b * IH3 + y + 1) * P3 + (xx + 1));
  const unsigned short* bp = blkpad + cbase * 32;
#pragma unroll
  for (int half = 0; half < 4; ++half) {
    U8 u; u.q = *(const uint4*)(bp + half * 8);
#pragma unroll
    for (int j = 0; j < 8; ++j) {
      float iv = bf2f(u.u[j]);
      int ci = half * 8 + j;
#pragma unroll
      for (int co = 0; co < 8; ++co) acc[co] += iv * wl[ci * 8 + co];
    }
  }
  U8 hv; hv.q = *(const uint4*)(h4raw + (size_t)p * 8);
  U8 o;
#pragma unroll
  for (int co = 0; co < 8; ++co) {
    float f = fmaxf(bf2f(hv.u[co]) * scale[b * 8 + co] + shift[b * 8 + co], 0.0f) + acc[co];
    o.u[co] = f2bf(f);
  }
  *(uint4*)(blk2pad + cbase * 8) = o.q;
}

// ---------------------------------------------------------------- conv5 direct (8->2, 3x3)
__global__ void k_conv5(const unsigned short* __restrict__ blk2pad, const float* __restrict__ w5,
                        const float* __restrict__ b5, float* __restrict__ h5) {
  __shared__ float wl[144];
  if (threadIdx.x < 144) {
    int i = threadIdx.x;
    int t = i / 16, r2 = i % 16, ci = r2 >> 1, co = r2 & 1;
    wl[i] = w5[(co * 8 + ci) * 9 + t];
  }
  __syncthreads();
  int p = blockIdx.x * 256 + threadIdx.x;
  int b = p / HW, r = p % HW, y = r / W, xx = r % W;
  float a0 = b5[0], a1 = b5[1];
#pragma unroll
  for (int t = 0; t < 9; ++t) {
    int ky = t / 3, kx = t % 3;
    const unsigned short* ip = blk2pad + ((size_t)(b * IH3 + y + ky) * P3 + (xx + kx)) * 8;
    U8 u; u.q = *(const uint4*)ip;
#pragma unroll
    for (int ci = 0; ci < 8; ++ci) {
      float iv = bf2f(u.u[ci]);
      a0 += iv * wl[t * 16 + ci * 2];
      a1 += iv * wl[t * 16 + ci * 2 + 1];
    }
  }
  h5[(size_t)p * 2] = a0;
  h5[(size_t)p * 2 + 1] = a1;
}

// ---------------------------------------------------------------- joint bilateral + tanh + scale
__global__ void k_bilateral(const float* __restrict__ h5, const float* __restrict__ x,
                            float* __restrict__ out, int nTot) {
  int p = blockIdx.x * 256 + threadIdx.x;
  if (p >= nTot) return;
  int b = p / HW, r = p % HW, y = r / W, xx = r % W;
  const float* xb = x + (size_t)b * HW;
  float xc = xb[r];
  float e1 = expf(-1.0f / 4.5f), e0 = expf(-4.0f / 4.5f);
  float gs = 1.0f + 2.0f * e1 + 2.0f * e0;
  float g[5] = {e0 / gs, e1 / gs, 1.0f / gs, e1 / gs, e0 / gs};
  float n0 = 0.0f, n1 = 0.0f, den = 0.0f;
#pragma unroll
  for (int dy = 0; dy < 5; ++dy) {
    int yn = y + dy - 2;
    yn = yn < 0 ? -yn : (yn >= H ? 2 * H - 2 - yn : yn);
#pragma unroll
    for (int dx = 0; dx < 5; ++dx) {
      int xn = xx + dx - 2;
      xn = xn < 0 ? -xn : (xn >= W ? 2 * W - 2 - xn : xn);
      float xv = xb[yn * W + xn];
      float d = xv - xc;
      float wgt = g[dy] * g[dx] * expf(-200.0f * d * d);
      den += wgt;
      const float* hp = h5 + ((size_t)(b * HW) + yn * W + xn) * 2;
      n0 += wgt * hp[0];
      n1 += wgt * hp[1];
    }
  }
  float o0 = tanhf(n0 / den) * 0.436f;
  float o1 = tanhf(n1 / den) * 0.615f;
  out[(size_t)(b * 2) * HW + r] = o0;
  out[(size_t)(b * 2 + 1) * HW + r] = o1;
}

// ---------------------------------------------------------------- host
extern "C" void kernel_launch(void* const* d_in, const int* in_sizes, int n_in,
                              void* d_out, int out_size, void* d_ws, size_t ws_size,
                              hipStream_t stream) {
  (void)in_sizes; (void)n_in; (void)out_size;
  const float* x   = (const float*)d_in[0];
  const float* w1  = (const float*)d_in[1];
  const float* b1  = (const float*)d_in[2];
  const float* g1w = (const float*)d_in[3];
  const float* g1b = (const float*)d_in[4];
  const float* w2  = (const float*)d_in[5];
  const float* b2  = (const float*)d_in[6];
  const float* g2w = (const float*)d_in[7];
  const float* g2b = (const float*)d_in[8];
  const float* w3  = (const float*)d_in[9];
  const float* b3  = (const float*)d_in[10];
  const float* g3w = (const float*)d_in[11];
  const float* g3b = (const float*)d_in[12];
  const float* w4  = (const float*)d_in[13];
  const float* b4  = (const float*)d_in[14];
  const float* g4w = (const float*)d_in[15];
  const float* g4b = (const float*)d_in[16];
  const float* w5  = (const float*)d_in[17];
  const float* b5  = (const float*)d_in[18];
  const float* sw1 = (const float*)d_in[19];
  const float* sb1 = (const float*)d_in[20];
  const float* sw2 = (const float*)d_in[21];
  const float* sb2 = (const float*)d_in[22];
  float* out = (float*)d_out;
  char* ws = (char*)d_ws;

  auto AL = [](size_t v) { return (v + 255) & ~(size_t)255; };
  const size_t sSPAD  = (size_t)IH5 * P5 * 128 * 2;
  const size_t sANG   = (size_t)HW * 8 * 4;
  const size_t sH1RAW = (size_t)HW * 64 * 2;
  const size_t sH1PAD = (size_t)IH3 * P3 * 64 * 2;
  const size_t sH2RAW = (size_t)HW * 32 * 2;
  const size_t sBLKP  = (size_t)IH3 * P3 * 32 * 2;
  const size_t sH3RAW = (size_t)HW * 16 * 2;
  const size_t sH3PAD = (size_t)IH3 * P3 * 16 * 2;
  const size_t sH4RAW = (size_t)HW * 8 * 2;
  const size_t sBLK2  = (size_t)IH3 * P3 * 8 * 2;

  int nb = 0;
  size_t offB = 0, offH1PAD = 0, offSmall = 0;
  const size_t smallFixed = AL(1024 * 1024) + AL((size_t)4 * 1080 * 16 * 4) + 8 * 4096;
  for (int cand = 4; cand >= 1; cand >>= 1) {
    size_t oB   = AL((size_t)cand * sSPAD);
    size_t oH1P = AL(oB + (size_t)cand * sH1RAW);
    size_t oS   = AL(oH1P + (size_t)cand * sH1PAD);
    size_t need = oS + smallFixed + AL((size_t)cand * sH2RAW);
    if (ws_size >= need) { nb = cand; offB = oB; offH1PAD = oH1P; offSmall = oS; break; }
  }
  if (nb == 0) {
    k_fill<<<(BN * 2 * HW + 255) / 256, 256, 0, stream>>>(out, BN * 2 * HW, 123.0f);
    return;
  }

  size_t oWB1  = offSmall;
  size_t oWB2  = AL(oWB1 + 25 * 64 * 128 * 2);
  size_t oWB3  = AL(oWB2 + 9 * 32 * 64 * 2);
  size_t oWBS  = AL(oWB3 + 9 * 16 * 32 * 2);
  size_t oPART = AL(oWBS + 32 * 128 * 2);
  size_t oSC1  = AL(oPART + (size_t)4 * 1080 * 16 * 4);
  size_t oSC2  = oSC1 + 4096, oSC3 = oSC2 + 4096, oSC4 = oSC3 + 4096;
  size_t oSK1  = oSC4 + 4096;

  unsigned short* wb1  = (unsigned short*)(ws + oWB1);
  unsigned short* wb2  = (unsigned short*)(ws + oWB2);
  unsigned short* wb3  = (unsigned short*)(ws + oWB3);
  unsigned short* wbs1 = (unsigned short*)(ws + oWBS);
  float* part = (float*)(ws + oPART);
  float* sc1 = (float*)(ws + oSC1); float* sh1 = sc1 + nb * 64;
  float* sc2 = (float*)(ws + oSC2); float* sh2 = sc2 + nb * 32;
  float* sc3 = (float*)(ws + oSC3); float* sh3 = sc3 + nb * 16;
  float* sc4 = (float*)(ws + oSC4); float* sh4 = sc4 + nb * 8;
  unsigned short* sk1 = (unsigned short*)(ws + oSK1);

  k_prep<128, 64, 5><<<800, 256, 0, stream>>>(w1, wb1);
  k_prep<64, 32, 3><<<72, 256, 0, stream>>>(w2, wb2);
  k_prep<32, 16, 3><<<18, 256, 0, stream>>>(w3, wb3);
  k_prep<128, 32, 1><<<16, 256, 0, stream>>>(sw1, wbs1);

  size_t t0 = AL((size_t)nb * sBLKP);
  size_t t1 = AL(t0 + (size_t)nb * sH3RAW);
  size_t t2 = AL(t1 + (size_t)nb * sH3PAD);
  size_t t3 = AL(t2 + (size_t)nb * sH4RAW);
  size_t t4 = AL(t3 + (size_t)nb * sBLK2);

  for (int b0 = 0; b0 < BN; b0 += nb) {
    const float* x_c = x + (size_t)b0 * HW;
    float* out_c = out + (size_t)b0 * 2 * HW;
    unsigned short* spad   = (unsigned short*)(ws);
    float*          ang    = (float*)(ws + offB);
    float*          pooled = (float*)(ws + AL(offB + (size_t)nb * sANG));
    unsigned short* h1raw  = (unsigned short*)(ws + offB);
    unsigned short* h1pad  = (unsigned short*)(ws + offH1PAD);
    unsigned short* h2raw  = (unsigned short*)(ws + offB);
    unsigned short* blkpad = (unsigned short*)(ws);
    unsigned short* h3raw  = (unsigned short*)(ws + t0);
    unsigned short* h3pad  = (unsigned short*)(ws + t1);
    unsigned short* h4raw  = (unsigned short*)(ws + t2);
    unsigned short* blk2   = (unsigned short*)(ws + t3);
    float*          h5     = (float*)(ws + t4);
    int nHW = nb * HW;
    int nbid = nb * H;

    // halo-only zeroing (interiors fully overwritten each chunk)
    k_halo<128, 2><<<(nb * 50304 + 255) / 256, 256, 0, stream>>>(spad, IH5, P5, nb);
    k_halo<64, 1><<<(nb * 12544 + 255) / 256, 256, 0, stream>>>(h1pad, IH3, P3, nb);

    k_sift_ang<<<nb * 540, 256, 0, stream>>>(x_c, ang, nHW);
    int nPP = nb * (H + 1) * (W + 1);
    k_sift_pool<<<(nPP + 255) / 256, 256, 0, stream>>>(ang, pooled, nPP);
    k_sift_desc<<<nHW / 4, 256, 0, stream>>>(pooled, spad);

    // conv1 (5x5, 128->64), 1 block/CU (107 KB LDS)
    k_convr<128, 64, 5, 8, 0, 1><<<nbid, 256, 0, stream>>>(spad, IH5, P5, wb1, b1, h1raw, part, nbid);
    k_gn_fin<64, 8><<<nb * 8, 64, 0, stream>>>(part, H, g1w, g1b, sc1, sh1, 1.0f / (8.0f * HW));
    k_norm<64, false><<<nb * 4320, 256, 0, stream>>>(h1raw, nullptr, sc1, sh1, h1pad);

    // conv2 (3x3, 64->32)
    k_convr<64, 32, 3, 8, 0, 2><<<nbid, 256, 0, stream>>>(h1pad, IH3, P3, wb2, b2, h2raw, part, nbid);
    k_gn_fin<32, 8><<<nb * 8, 64, 0, stream>>>(part, H, g2w, g2b, sc2, sh2, 1.0f / (4.0f * HW));
    // skip1 (1x1, 128->32) on spad
    k_convr<128, 32, 1, 0, 2, 2><<<nbid, 256, 0, stream>>>(spad, IH5, P5, wbs1, sb1, sk1, nullptr, nbid);

    // spad dead; its region hosts blkpad + tail buffers
    k_halo<32, 1><<<(nb * 6272 + 255) / 256, 256, 0, stream>>>(blkpad, IH3, P3, nb);
    k_halo<16, 1><<<(nb * 3136 + 255) / 256, 256, 0, stream>>>(h3pad, IH3, P3, nb);
    k_halo<8, 1><<<(nb * 1568 + 255) / 256, 256, 0, stream>>>(blk2, IH3, P3, nb);

    k_norm<32, true><<<nb * 2160, 256, 0, stream>>>(h2raw, sk1, sc2, sh2, blkpad);

    // conv3 (3x3, 32->16)
    k_convr<32, 16, 3, 4, 0, 2><<<nbid, 256, 0, stream>>>(blkpad, IH3, P3, wb3, b3, h3raw, part, nbid);
    k_gn_fin<16, 4><<<nb * 4, 64, 0, stream>>>(part, H, g3w, g3b, sc3, sh3, 1.0f / (4.0f * HW));
    k_norm<16, false><<<nb * 1080, 256, 0, stream>>>(h3raw, nullptr, sc3, sh3, h3pad);

    k_conv4<<<nb * 540, 256, 0, stream>>>(h3pad, w4, b4, h4raw, part);
    k_gn_fin<8, 4><<<nb * 4, 64, 0, stream>>>(part, 540, g4w, g4b, sc4, sh4, 1.0f / (2.0f * HW));
    k_norm4<<<nb * 540, 256, 0, stream>>>(h4raw, blkpad, sc4, sh4, sw2, sb2, blk2);

    k_conv5<<<nb * 540, 256, 0, stream>>>(blk2, w5, b5, h5);
    k_bilateral<<<nb * 540, 256, 0, stream>>>(h5, x_c, out_c, nHW);
  }
}

// Round 7
// 728.998 us; speedup vs baseline: 1.1619x; 1.1072x over previous
//
#include <hip/hip_runtime.h>

#define DEV __device__ __forceinline__

typedef __bf16 bf16x8 __attribute__((ext_vector_type(8)));
typedef float f32x4 __attribute__((ext_vector_type(4)));

union U8 { uint4 q; unsigned short u[8]; };

constexpr int BN = 4, H = 270, W = 512, HW = H * W;
constexpr int IH5 = 274, P5 = 516;   // pad-2 buffers (SIFT descriptor)
constexpr int IH3 = 272, P3 = 514;   // pad-1 buffers

DEV unsigned short f2bf(float f) {
  unsigned int u = __builtin_bit_cast(unsigned int, f);
  u = (u + 0x7FFFu + ((u >> 16) & 1u)) >> 16;
  return (unsigned short)u;
}
DEV float bf2f(unsigned short h) {
  return __builtin_bit_cast(float, (unsigned int)h << 16);
}

#define GLL16(g, l)                                                                        \
  __builtin_amdgcn_global_load_lds((const __attribute__((address_space(1))) void*)(g),     \
                                   (__attribute__((address_space(3))) void*)(l), 16, 0, 0)

// swizzle: XOR 16B-slot with ((row>>1)&3) -> 2-way (free) bank aliasing on stride-64B reads
DEV int swz(int row) { return ((row >> 1) & 3) << 4; }

// ---------------------------------------------------------------- diagnostic
__global__ void k_fill(float* __restrict__ out, int n, float v) {
  int i = blockIdx.x * 256 + threadIdx.x;
  if (i < n) out[i] = v;
}

// ---------------------------------------------------------------- halo zero
template <int C, int PD>
__global__ void k_halo(unsigned short* __restrict__ buf, int IHt, int pitch, int nb_) {
  int vPerRow = pitch * C / 8;
  int topBot = 2 * PD * vPerRow;
  int sideV = PD * C / 8;
  int midRows = IHt - 2 * PD;
  int perS = topBot + midRows * 2 * sideV;
  int v = blockIdx.x * 256 + threadIdx.x;
  if (v >= nb_ * perS) return;
  int s = v / perS, r = v % perS;
  size_t base = (size_t)s * IHt * pitch * C;
  size_t off;
  if (r < topBot) {
    int half = r / (PD * vPerRow);
    int rr = r % (PD * vPerRow);
    off = ((size_t)(half ? (IHt - PD) : 0) * pitch * C) + (size_t)rr * 8;
  } else {
    int r2 = r - topBot;
    int row = r2 / (2 * sideV), c2 = r2 % (2 * sideV);
    int side = c2 / sideV, cc = c2 % sideV;
    off = ((size_t)(PD + row) * pitch + (side ? (pitch - PD) : 0)) * C + (size_t)cc * 8;
  }
  *(uint4*)(buf + base + off) = uint4{0, 0, 0, 0};
}

// ---------------------------------------------------------------- SIFT stage 1
__global__ void k_sift_ang(const float* __restrict__ x, float* __restrict__ ang, int nTot) {
  int p = blockIdx.x * 256 + threadIdx.x;
  if (p >= nTot) return;
  int b = p / HW, r = p % HW, y = r / W, xx = r % W;
  const float* xb = x + (size_t)b * HW;
  float xm = xb[y * W + (xx > 0 ? xx - 1 : 0)];
  float xp = xb[y * W + (xx < W - 1 ? xx + 1 : W - 1)];
  float ym = xb[(y > 0 ? y - 1 : 0) * W + xx];
  float yp = xb[(y < H - 1 ? y + 1 : H - 1) * W + xx];
  float gx = (xp - xm) * 0.5f, gy = (yp - ym) * 0.5f;
  float mag = sqrtf(gx * gx + gy * gy + 1e-10f);
  float ori = atan2f(gy, gx + 1e-10f) + 6.2831855f;
  float o = (8.0f * ori) / 6.2831855f;
  float bo0f = floorf(o);
  float wo1 = o - bo0f;
  int b0 = ((int)bo0f) & 7;
  int b1 = (b0 + 1) & 7;
  float w0m = (1.0f - wo1) * mag, w1m = wo1 * mag;
  float v[8];
#pragma unroll
  for (int k = 0; k < 8; ++k)
    v[k] = (k == b0 ? w0m : 0.0f) + (k == b1 ? w1m : 0.0f);
  float4* o4 = (float4*)(ang + (size_t)p * 8);
  o4[0] = make_float4(v[0], v[1], v[2], v[3]);
  o4[1] = make_float4(v[4], v[5], v[6], v[7]);
}

// ---------------------------------------------------------------- SIFT stage 2
__global__ void k_sift_pool(const float* __restrict__ ang, float* __restrict__ pooled, int nTot) {
  constexpr int PH = H + 1, PW = W + 1;
  int p = blockIdx.x * 256 + threadIdx.x;
  if (p >= nTot) return;
  int b = p / (PH * PW), r = p % (PH * PW), y = r / PW, xx = r % PW;
  float4 a0 = {0, 0, 0, 0}, a1 = {0, 0, 0, 0};
  const float xc2[4] = {0.5f, 1.5f, 1.5f, 0.5f};
#pragma unroll
  for (int ky = 0; ky < 4; ++ky) {
    int yy = y - 2 + ky;
    if (yy < 0 || yy >= H) continue;
#pragma unroll
    for (int kx = 0; kx < 4; ++kx) {
      int xs = xx - 2 + kx;
      if (xs < 0 || xs >= W) continue;
      float w = xc2[ky] * xc2[kx] * 0.25f;
      const float4* s4 = (const float4*)(ang + ((size_t)(b * H + yy) * W + xs) * 8);
      float4 v0 = s4[0], v1 = s4[1];
      a0.x += w * v0.x; a0.y += w * v0.y; a0.z += w * v0.z; a0.w += w * v0.w;
      a1.x += w * v1.x; a1.y += w * v1.y; a1.z += w * v1.z; a1.w += w * v1.w;
    }
  }
  float4* o4 = (float4*)(pooled + (size_t)p * 8);
  o4[0] = a0; o4[1] = a1;
}

// ---------------------------------------------------------------- SIFT stage 3
__global__ void k_sift_desc(const float* __restrict__ pooled, unsigned short* __restrict__ spad) {
  constexpr int PH = H + 1, PW = W + 1;
  int tid = threadIdx.x;
  int wv = tid >> 6, lane = tid & 63;
  int p = blockIdx.x * 4 + wv;
  int b = p / HW, r = p % HW, yy = r / W, xx = r % W;
  int a = lane >> 3, jj = lane & 7;
  int j0 = jj * 2;
  int dy = j0 >> 2, dx = j0 & 3;
  int rr = yy + dy - 1;
  int c0 = xx + dx - 1, c1 = c0 + 1;
  bool rv = (rr >= 0 && rr <= H);
  int rc = min(max(rr, 0), H);
  const float* pb = pooled + ((size_t)(b * PH + rc) * PW) * 8 + a;
  float v0 = 0.0f, v1 = 0.0f;
  if (rv && c0 >= 0 && c0 <= W) v0 = pb[(size_t)c0 * 8];
  if (rv && c1 >= 0 && c1 <= W) v1 = pb[(size_t)c1 * 8];

  float n2 = v0 * v0 + v1 * v1;
#pragma unroll
  for (int m = 1; m < 64; m <<= 1) n2 += __shfl_xor(n2, m);
  float inv = 1.0f / fmaxf(sqrtf(n2), 1e-12f);
  v0 = fminf(v0 * inv, 0.2f);
  v1 = fminf(v1 * inv, 0.2f);
  float n2b = v0 * v0 + v1 * v1;
#pragma unroll
  for (int m = 1; m < 64; m <<= 1) n2b += __shfl_xor(n2b, m);
  inv = 1.0f / fmaxf(sqrtf(n2b), 1e-12f);
  v0 *= inv; v1 *= inv;
  float l1 = v0 + v1;
#pragma unroll
  for (int m = 1; m < 64; m <<= 1) l1 += __shfl_xor(l1, m);
  float il1 = 1.0f / fmaxf(l1, 1e-12f);
  v0 = sqrtf(v0 * il1 + 1e-10f);
  v1 = sqrtf(v1 * il1 + 1e-10f);
  unsigned int pk = (unsigned int)f2bf(v0) | ((unsigned int)f2bf(v1) << 16);
  *(unsigned int*)(spad + ((size_t)(b * IH5 + yy + 2) * P5 + xx + 2) * 128 + lane * 2) = pk;
}

// ---------------------------------------------------------------- weight prep: [t][co][ci] bf16
template <int CIN, int COUT, int KS>
__global__ void k_prep(const float* __restrict__ w, unsigned short* __restrict__ wbuf) {
  int i = blockIdx.x * 256 + threadIdx.x;
  if (i >= KS * KS * COUT * CIN) return;
  int t = i / (COUT * CIN), r2 = i % (COUT * CIN), co = r2 / CIN, e = r2 % CIN;
  wbuf[i] = f2bf(w[(co * CIN + e) * (KS * KS) + t]);
}

// ---------------------------------------------------------------- full-row MFMA conv, 512 threads
// Block = one output row (512 px), 8 waves x 64 px, all COUT.
// Unit between barriers = one (ci-quarter q, ky): slab row + W ky-row, double-buffered,
// staged via global_load_lds with pre-swizzled source. Optional fused center-tap 1x1 skip.
template <int CIN, int COUT, int KS, int NG, int PADOFF, int MINB, bool FSKIP>
__launch_bounds__(512, MINB)
__global__ void k_convr(const unsigned short* __restrict__ in, int IHt, int ipitch,
                        const unsigned short* __restrict__ wtap,
                        const float* __restrict__ bias,
                        const unsigned short* __restrict__ wsk,
                        const float* __restrict__ skb,
                        unsigned short* __restrict__ outraw,
                        unsigned short* __restrict__ skraw,
                        float* __restrict__ part, int nbid) {
  constexpr int SLABPX = 512 + KS - 1;
  constexpr int KQ = CIN / 32;
  constexpr int NF = COUT / 16;
  constexpr int SLAB = SLABPX * 64;     // 64 B per px (32 ci * bf16)
  constexpr int SWQ = COUT * 64;        // one tap's ci-quarter of W
  constexpr int SWROW = KS * SWQ;       // full ky-row of W
  constexpr int SSK = FSKIP ? 32 * 64 : 16;
  __shared__ __align__(16) unsigned char slabB[2][SLAB];
  __shared__ __align__(16) unsigned char wrowB[2][SWROW];
  __shared__ __align__(16) unsigned char wskB[2][SSK];
  __shared__ float red[8][16];

  int tid = threadIdx.x;
  int lane = tid & 63, wid = tid >> 6;
  int l15 = lane & 15, hi = lane >> 4;

  // bijective XCD chunk remap (m204)
  int bid = blockIdx.x;
  int q8 = nbid >> 3, r8 = nbid & 7;
  int xcd = bid & 7;
  int by = (xcd < r8 ? xcd * (q8 + 1) : r8 * (q8 + 1) + (xcd - r8) * q8) + (bid >> 3);
  int y = by % H, b = by / H;

  f32x4 acc[4][NF] = {};
  f32x4 ask[4][2] = {};

  auto stage = [&](int it, int pbuf) {
    int q = it / KS, ky = it % KS;
    const char* src = (const char*)(in + ((size_t)(b * IHt + y + ky + PADOFF) * ipitch + PADOFF) * CIN + q * 32);
    for (int d = tid * 16; d < SLAB; d += 8192) {
      int px = d >> 6, qb = d & 63;
      GLL16(src + px * (CIN * 2) + (qb ^ swz(px)), slabB[pbuf] + d);
    }
    const char* wsrc = (const char*)wtap + (size_t)(ky * KS) * (COUT * CIN * 2) + q * 64;
    for (int d = tid * 16; d < SWROW; d += 8192) {
      int kx = d / SWQ, rem = d % SWQ;
      int co = rem >> 6, qb = rem & 63;
      GLL16(wsrc + (size_t)kx * (COUT * CIN * 2) + co * (CIN * 2) + (qb ^ swz(co)), wrowB[pbuf] + d);
    }
  };
  auto stage_wsk = [&](int q, int pbuf) {
    const char* src = (const char*)wsk + q * 64;
    for (int d = tid * 16; d < 32 * 64; d += 8192) {
      int co = d >> 6, qb = d & 63;
      GLL16(src + co * (CIN * 2) + (qb ^ swz(co)), wskB[pbuf] + d);
    }
  };

  stage(0, 0);
  if constexpr (FSKIP) stage_wsk(0, 0);
  __syncthreads();   // compiler drains vmcnt before barrier -> staged data visible

#pragma unroll 1
  for (int it = 0; it < KQ * KS; ++it) {
    int cur = it & 1;
    int q = it / KS, ky = it % KS;
    if (it + 1 < KQ * KS) {
      stage(it + 1, cur ^ 1);   // overlap with compute below
      if (FSKIP && (it + 1) % KS == 0) stage_wsk((it + 1) / KS, ((it + 1) / KS) & 1);
    }
    const unsigned char* sl = slabB[cur];
    const unsigned char* wr = wrowB[cur];
    int koff = hi * 16;
#pragma unroll
    for (int kx = 0; kx < KS; ++kx) {
      bf16x8 af[4];
#pragma unroll
      for (int mi = 0; mi < 4; ++mi) {
        int px = wid * 64 + mi * 16 + l15 + kx;
        af[mi] = *(const bf16x8*)(sl + px * 64 + (koff ^ swz(px)));
      }
#pragma unroll
      for (int ni = 0; ni < NF; ++ni) {
        int co = ni * 16 + l15;
        bf16x8 bq = *(const bf16x8*)(wr + kx * SWQ + co * 64 + (koff ^ swz(co)));
#pragma unroll
        for (int mi = 0; mi < 4; ++mi)
          acc[mi][ni] = __builtin_amdgcn_mfma_f32_16x16x32_bf16(af[mi], bq, acc[mi][ni], 0, 0, 0);
      }
      if constexpr (FSKIP) {
        if (ky == KS / 2 && kx == KS / 2) {
#pragma unroll
          for (int ni = 0; ni < 2; ++ni) {
            int co = ni * 16 + l15;
            bf16x8 bq = *(const bf16x8*)(wskB[q & 1] + co * 64 + (koff ^ swz(co)));
#pragma unroll
            for (int mi = 0; mi < 4; ++mi)
              ask[mi][ni] = __builtin_amdgcn_mfma_f32_16x16x32_bf16(af[mi], bq, ask[mi][ni], 0, 0, 0);
          }
        }
      }
    }
    __syncthreads();   // my reads of buf[cur] done; stage(it+1) drained -> next iter safe
  }

  // bias
#pragma unroll
  for (int ni = 0; ni < NF; ++ni) {
    float bv = bias[ni * 16 + l15];
#pragma unroll
    for (int mi = 0; mi < 4; ++mi)
#pragma unroll
      for (int rr = 0; rr < 4; ++rr)
        acc[mi][ni][rr] += bv;
  }
  // store raw NHWC bf16
  unsigned short* op = outraw + ((size_t)(b * H + y) * W) * COUT;
#pragma unroll
  for (int mi = 0; mi < 4; ++mi)
#pragma unroll
    for (int rr = 0; rr < 4; ++rr) {
      int px = wid * 64 + mi * 16 + hi * 4 + rr;
#pragma unroll
      for (int ni = 0; ni < NF; ++ni)
        op[(size_t)px * COUT + ni * 16 + l15] = f2bf(acc[mi][ni][rr]);
    }
  // fused skip output
  if constexpr (FSKIP) {
    unsigned short* ops = skraw + ((size_t)(b * H + y) * W) * 32;
#pragma unroll
    for (int ni = 0; ni < 2; ++ni) {
      float bv = skb[ni * 16 + l15];
#pragma unroll
      for (int mi = 0; mi < 4; ++mi)
#pragma unroll
        for (int rr = 0; rr < 4; ++rr)
          ask[mi][ni][rr] += bv;
    }
#pragma unroll
    for (int mi = 0; mi < 4; ++mi)
#pragma unroll
      for (int rr = 0; rr < 4; ++rr) {
        int px = wid * 64 + mi * 16 + hi * 4 + rr;
#pragma unroll
        for (int ni = 0; ni < 2; ++ni)
          ops[(size_t)px * 32 + ni * 16 + l15] = f2bf(ask[mi][ni][rr]);
      }
  }
  // deterministic per-row GN partials (slot = global row index)
  if constexpr (NG > 0) {
    constexpr int GPC = COUT / NG;
#pragma unroll
    for (int ni = 0; ni < NF; ++ni) {
      float s = 0.0f, q2 = 0.0f;
#pragma unroll
      for (int mi = 0; mi < 4; ++mi)
#pragma unroll
        for (int rr = 0; rr < 4; ++rr) {
          float v = acc[mi][ni][rr];
          s += v; q2 += v * v;
        }
      s += __shfl_xor(s, 16); q2 += __shfl_xor(q2, 16);
      s += __shfl_xor(s, 32); q2 += __shfl_xor(q2, 32);
#pragma unroll
      for (int m = 1; m < GPC; m <<= 1) { s += __shfl_xor(s, m); q2 += __shfl_xor(q2, m); }
      if (hi == 0 && (l15 % GPC) == 0) {
        int g = ni * (16 / GPC) + l15 / GPC;
        red[wid][g] = s;
        red[wid][NG + g] = q2;
      }
    }
    __syncthreads();
    if (tid < 2 * NG) {
      float t = 0.0f;
#pragma unroll
      for (int wv2 = 0; wv2 < 8; ++wv2) t += red[wv2][tid];
      part[(size_t)by * (2 * NG) + tid] = t;
    }
  }
}

// ---------------------------------------------------------------- GN finalize
template <int COUT, int NG>
__global__ void k_gn_fin(const float* __restrict__ part, int NB,
                         const float* __restrict__ gw, const float* __restrict__ gb,
                         float* __restrict__ scale, float* __restrict__ shift, float invN) {
  constexpr int GPC = COUT / NG;
  int b = blockIdx.x / NG, g = blockIdx.x % NG;
  int lane = threadIdx.x;
  float s = 0.0f, q = 0.0f;
  for (int i = lane; i < NB; i += 64) {
    const float* pp = part + (size_t)(b * NB + i) * (2 * NG);
    s += pp[g]; q += pp[NG + g];
  }
#pragma unroll
  for (int m = 1; m < 64; m <<= 1) { s += __shfl_xor(s, m); q += __shfl_xor(q, m); }
  if (lane == 0) {
    float mean = s * invN;
    float var = q * invN - mean * mean;
    float rstd = rsqrtf(var + 1e-5f);
#pragma unroll
    for (int j = 0; j < GPC; ++j) {
      int c = g * GPC + j;
      float sc = gw[c] * rstd;
      scale[b * COUT + c] = sc;
      shift[b * COUT + c] = gb[c] - mean * sc;
    }
  }
}

// ---------------------------------------------------------------- GN-apply (+ReLU, +skip)
template <int C, bool ADDSKIP>
__global__ void k_norm(const unsigned short* __restrict__ raw,
                       const unsigned short* __restrict__ skip,
                       const float* __restrict__ scale, const float* __restrict__ shift,
                       unsigned short* __restrict__ outpad) {
  int e = blockIdx.x * 256 + threadIdx.x;
  int idx = e * 8;
  int p = idx / C, c0 = idx % C;
  int b = p / HW, r = p % HW, y = r / W, xx = r % W;
  U8 v; v.q = *(const uint4*)(raw + (size_t)p * C + c0);
  U8 sk;
  if (ADDSKIP) sk.q = *(const uint4*)(skip + (size_t)p * C + c0);
  const float* sc = scale + b * C + c0;
  const float* sh = shift + b * C + c0;
  U8 o;
#pragma unroll
  for (int j = 0; j < 8; ++j) {
    float f = fmaxf(bf2f(v.u[j]) * sc[j] + sh[j], 0.0f);
    if (ADDSKIP) f += bf2f(sk.u[j]);
    o.u[j] = f2bf(f);
  }
  *(uint4*)(outpad + ((size_t)(b * IH3 + y + 1) * P3 + xx + 1) * C + c0) = o.q;
}

// ---------------------------------------------------------------- conv4 direct (16->8, 3x3)
__global__ void k_conv4(const unsigned short* __restrict__ h3pad, const float* __restrict__ w4,
                        const float* __restrict__ b4, unsigned short* __restrict__ h4raw,
                        float* __restrict__ part) {
  __shared__ float wl[1152];
  __shared__ float red[4][8];
  for (int i = threadIdx.x; i < 1152; i += 256) {
    int t = i / 128, r2 = i % 128, ci = r2 >> 3, co = r2 & 7;
    wl[i] = w4[(co * 16 + ci) * 9 + t];
  }
  __syncthreads();
  int p = blockIdx.x * 256 + threadIdx.x;
  int b = p / HW, r = p % HW, y = r / W, xx = r % W;
  float acc[8];
#pragma unroll
  for (int co = 0; co < 8; ++co) acc[co] = b4[co];
#pragma unroll
  for (int t = 0; t < 9; ++t) {
    int ky = t / 3, kx = t % 3;
    const unsigned short* ip = h3pad + ((size_t)(b * IH3 + y + ky) * P3 + (xx + kx)) * 16;
    U8 u0, u1;
    u0.q = *(const uint4*)ip;
    u1.q = *(const uint4*)(ip + 8);
#pragma unroll
    for (int ci = 0; ci < 16; ++ci) {
      float iv = bf2f(ci < 8 ? u0.u[ci] : u1.u[ci - 8]);
#pragma unroll
      for (int co = 0; co < 8; ++co)
        acc[co] += iv * wl[t * 128 + ci * 8 + co];
    }
  }
  int lane = threadIdx.x & 63, wv = threadIdx.x >> 6;
  float s[4], q[4];
#pragma unroll
  for (int g = 0; g < 4; ++g) {
    s[g] = acc[2 * g] + acc[2 * g + 1];
    q[g] = acc[2 * g] * acc[2 * g] + acc[2 * g + 1] * acc[2 * g + 1];
  }
#pragma unroll
  for (int m = 1; m < 64; m <<= 1) {
#pragma unroll
    for (int g = 0; g < 4; ++g) { s[g] += __shfl_xor(s[g], m); q[g] += __shfl_xor(q[g], m); }
  }
  if (lane == 0) {
#pragma unroll
    for (int g = 0; g < 4; ++g) { red[wv][g] = s[g]; red[wv][4 + g] = q[g]; }
  }
  __syncthreads();
  if (threadIdx.x < 8)
    part[(size_t)blockIdx.x * 8 + threadIdx.x] =
        red[0][threadIdx.x] + red[1][threadIdx.x] + red[2][threadIdx.x] + red[3][threadIdx.x];
  U8 o;
#pragma unroll
  for (int co = 0; co < 8; ++co) o.u[co] = f2bf(acc[co]);
  *(uint4*)(h4raw + (size_t)p * 8) = o.q;
}

// ---------------------------------------------------------------- norm4 + skip2 (1x1 32->8)
__global__ void k_norm4(const unsigned short* __restrict__ h4raw, const unsigned short* __restrict__ blkpad,
                        const float* __restrict__ scale, const float* __restrict__ shift,
                        const float* __restrict__ sw2, const float* __restrict__ sb2,
                        unsigned short* __restrict__ blk2pad) {
  __shared__ float wl[256];
  {
    int i = threadIdx.x;
    int ci = i >> 3, co = i & 7;
    wl[i] = sw2[co * 32 + ci];
  }
  __syncthreads();
  int p = blockIdx.x * 256 + threadIdx.x;
  int b = p / HW, r = p % HW, y = r / W, xx = r % W;
  float acc[8];
#pragma unroll
  for (int co = 0; co < 8; ++co) acc[co] = sb2[co];
  size_t cbase = ((size_t)(b * IH3 + y + 1) * P3 + (xx + 1));
  const unsigned short* bp = blkpad + cbase * 32;
#pragma unroll
  for (int half = 0; half < 4; ++half) {
    U8 u; u.q = *(const uint4*)(bp + half * 8);
#pragma unroll
    for (int j = 0; j < 8; ++j) {
      float iv = bf2f(u.u[j]);
      int ci = half * 8 + j;
#pragma unroll
      for (int co = 0; co < 8; ++co) acc[co] += iv * wl[ci * 8 + co];
    }
  }
  U8 hv; hv.q = *(const uint4*)(h4raw + (size_t)p * 8);
  U8 o;
#pragma unroll
  for (int co = 0; co < 8; ++co) {
    float f = fmaxf(bf2f(hv.u[co]) * scale[b * 8 + co] + shift[b * 8 + co], 0.0f) + acc[co];
    o.u[co] = f2bf(f);
  }
  *(uint4*)(blk2pad + cbase * 8) = o.q;
}

// ---------------------------------------------------------------- conv5 direct (8->2, 3x3)
__global__ void k_conv5(const unsigned short* __restrict__ blk2pad, const float* __restrict__ w5,
                        const float* __restrict__ b5, float* __restrict__ h5) {
  __shared__ float wl[144];
  if (threadIdx.x < 144) {
    int i = threadIdx.x;
    int t = i / 16, r2 = i % 16, ci = r2 >> 1, co = r2 & 1;
    wl[i] = w5[(co * 8 + ci) * 9 + t];
  }
  __syncthreads();
  int p = blockIdx.x * 256 + threadIdx.x;
  int b = p / HW, r = p % HW, y = r / W, xx = r % W;
  float a0 = b5[0], a1 = b5[1];
#pragma unroll
  for (int t = 0; t < 9; ++t) {
    int ky = t / 3, kx = t % 3;
    const unsigned short* ip = blk2pad + ((size_t)(b * IH3 + y + ky) * P3 + (xx + kx)) * 8;
    U8 u; u.q = *(const uint4*)ip;
#pragma unroll
    for (int ci = 0; ci < 8; ++ci) {
      float iv = bf2f(u.u[ci]);
      a0 += iv * wl[t * 16 + ci * 2];
      a1 += iv * wl[t * 16 + ci * 2 + 1];
    }
  }
  h5[(size_t)p * 2] = a0;
  h5[(size_t)p * 2 + 1] = a1;
}

// ---------------------------------------------------------------- joint bilateral + tanh + scale
__global__ void k_bilateral(const float* __restrict__ h5, const float* __restrict__ x,
                            float* __restrict__ out, int nTot) {
  int p = blockIdx.x * 256 + threadIdx.x;
  if (p >= nTot) return;
  int b = p / HW, r = p % HW, y = r / W, xx = r % W;
  const float* xb = x + (size_t)b * HW;
  float xc = xb[r];
  float e1 = expf(-1.0f / 4.5f), e0 = expf(-4.0f / 4.5f);
  float gs = 1.0f + 2.0f * e1 + 2.0f * e0;
  float g[5] = {e0 / gs, e1 / gs, 1.0f / gs, e1 / gs, e0 / gs};
  float n0 = 0.0f, n1 = 0.0f, den = 0.0f;
#pragma unroll
  for (int dy = 0; dy < 5; ++dy) {
    int yn = y + dy - 2;
    yn = yn < 0 ? -yn : (yn >= H ? 2 * H - 2 - yn : yn);
#pragma unroll
    for (int dx = 0; dx < 5; ++dx) {
      int xn = xx + dx - 2;
      xn = xn < 0 ? -xn : (xn >= W ? 2 * W - 2 - xn : xn);
      float xv = xb[yn * W + xn];
      float d = xv - xc;
      float wgt = g[dy] * g[dx] * expf(-200.0f * d * d);
      den += wgt;
      const float* hp = h5 + ((size_t)(b * HW) + yn * W + xn) * 2;
      n0 += wgt * hp[0];
      n1 += wgt * hp[1];
    }
  }
  float o0 = tanhf(n0 / den) * 0.436f;
  float o1 = tanhf(n1 / den) * 0.615f;
  out[(size_t)(b * 2) * HW + r] = o0;
  out[(size_t)(b * 2 + 1) * HW + r] = o1;
}

// ---------------------------------------------------------------- host
extern "C" void kernel_launch(void* const* d_in, const int* in_sizes, int n_in,
                              void* d_out, int out_size, void* d_ws, size_t ws_size,
                              hipStream_t stream) {
  (void)in_sizes; (void)n_in; (void)out_size;
  const float* x   = (const float*)d_in[0];
  const float* w1  = (const float*)d_in[1];
  const float* b1  = (const float*)d_in[2];
  const float* g1w = (const float*)d_in[3];
  const float* g1b = (const float*)d_in[4];
  const float* w2  = (const float*)d_in[5];
  const float* b2  = (const float*)d_in[6];
  const float* g2w = (const float*)d_in[7];
  const float* g2b = (const float*)d_in[8];
  const float* w3  = (const float*)d_in[9];
  const float* b3  = (const float*)d_in[10];
  const float* g3w = (const float*)d_in[11];
  const float* g3b = (const float*)d_in[12];
  const float* w4  = (const float*)d_in[13];
  const float* b4  = (const float*)d_in[14];
  const float* g4w = (const float*)d_in[15];
  const float* g4b = (const float*)d_in[16];
  const float* w5  = (const float*)d_in[17];
  const float* b5  = (const float*)d_in[18];
  const float* sw1 = (const float*)d_in[19];
  const float* sb1 = (const float*)d_in[20];
  const float* sw2 = (const float*)d_in[21];
  const float* sb2 = (const float*)d_in[22];
  float* out = (float*)d_out;
  char* ws = (char*)d_ws;

  auto AL = [](size_t v) { return (v + 255) & ~(size_t)255; };
  const size_t sSPAD  = (size_t)IH5 * P5 * 128 * 2;
  const size_t sANG   = (size_t)HW * 8 * 4;
  const size_t sH1RAW = (size_t)HW * 64 * 2;
  const size_t sH1PAD = (size_t)IH3 * P3 * 64 * 2;
  const size_t sH2RAW = (size_t)HW * 32 * 2;
  const size_t sBLKP  = (size_t)IH3 * P3 * 32 * 2;
  const size_t sH3RAW = (size_t)HW * 16 * 2;
  const size_t sH3PAD = (size_t)IH3 * P3 * 16 * 2;
  const size_t sH4RAW = (size_t)HW * 8 * 2;
  const size_t sBLK2  = (size_t)IH3 * P3 * 8 * 2;

  int nb = 0;
  size_t offB = 0, offH1PAD = 0, offSmall = 0;
  const size_t smallFixed = AL(1024 * 1024) + AL((size_t)4 * 1080 * 16 * 4) + 8 * 4096;
  for (int cand = 4; cand >= 1; cand >>= 1) {
    size_t oB   = AL((size_t)cand * sSPAD);
    size_t oH1P = AL(oB + (size_t)cand * sH1RAW);
    size_t oS   = AL(oH1P + (size_t)cand * sH1PAD);
    size_t need = oS + smallFixed + AL((size_t)cand * sH2RAW);
    if (ws_size >= need) { nb = cand; offB = oB; offH1PAD = oH1P; offSmall = oS; break; }
  }
  if (nb == 0) {
    k_fill<<<(BN * 2 * HW + 255) / 256, 256, 0, stream>>>(out, BN * 2 * HW, 123.0f);
    return;
  }

  size_t oWB1  = offSmall;
  size_t oWB2  = AL(oWB1 + 25 * 64 * 128 * 2);
  size_t oWB3  = AL(oWB2 + 9 * 32 * 64 * 2);
  size_t oWBS  = AL(oWB3 + 9 * 16 * 32 * 2);
  size_t oPART = AL(oWBS + 32 * 128 * 2);
  size_t oSC1  = AL(oPART + (size_t)4 * 1080 * 16 * 4);
  size_t oSC2  = oSC1 + 4096, oSC3 = oSC2 + 4096, oSC4 = oSC3 + 4096;
  size_t oSK1  = oSC4 + 4096;

  unsigned short* wb1  = (unsigned short*)(ws + oWB1);
  unsigned short* wb2  = (unsigned short*)(ws + oWB2);
  unsigned short* wb3  = (unsigned short*)(ws + oWB3);
  unsigned short* wbs1 = (unsigned short*)(ws + oWBS);
  float* part = (float*)(ws + oPART);
  float* sc1 = (float*)(ws + oSC1); float* sh1 = sc1 + nb * 64;
  float* sc2 = (float*)(ws + oSC2); float* sh2 = sc2 + nb * 32;
  float* sc3 = (float*)(ws + oSC3); float* sh3 = sc3 + nb * 16;
  float* sc4 = (float*)(ws + oSC4); float* sh4 = sc4 + nb * 8;
  unsigned short* sk1 = (unsigned short*)(ws + oSK1);

  k_prep<128, 64, 5><<<800, 256, 0, stream>>>(w1, wb1);
  k_prep<64, 32, 3><<<72, 256, 0, stream>>>(w2, wb2);
  k_prep<32, 16, 3><<<18, 256, 0, stream>>>(w3, wb3);
  k_prep<128, 32, 1><<<16, 256, 0, stream>>>(sw1, wbs1);

  size_t t0 = AL((size_t)nb * sBLKP);
  size_t t1 = AL(t0 + (size_t)nb * sH3RAW);
  size_t t2 = AL(t1 + (size_t)nb * sH3PAD);
  size_t t3 = AL(t2 + (size_t)nb * sH4RAW);
  size_t t4 = AL(t3 + (size_t)nb * sBLK2);

  for (int b0 = 0; b0 < BN; b0 += nb) {
    const float* x_c = x + (size_t)b0 * HW;
    float* out_c = out + (size_t)b0 * 2 * HW;
    unsigned short* spad   = (unsigned short*)(ws);
    float*          ang    = (float*)(ws + offB);
    float*          pooled = (float*)(ws + AL(offB + (size_t)nb * sANG));
    unsigned short* h1raw  = (unsigned short*)(ws + offB);
    unsigned short* h1pad  = (unsigned short*)(ws + offH1PAD);
    unsigned short* h2raw  = (unsigned short*)(ws + offB);
    unsigned short* blkpad = (unsigned short*)(ws);
    unsigned short* h3raw  = (unsigned short*)(ws + t0);
    unsigned short* h3pad  = (unsigned short*)(ws + t1);
    unsigned short* h4raw  = (unsigned short*)(ws + t2);
    unsigned short* blk2   = (unsigned short*)(ws + t3);
    float*          h5     = (float*)(ws + t4);
    int nHW = nb * HW;
    int nbid = nb * H;

    // halo-only zeroing (interiors fully overwritten each chunk)
    k_halo<128, 2><<<(nb * 50304 + 255) / 256, 256, 0, stream>>>(spad, IH5, P5, nb);
    k_halo<64, 1><<<(nb * 12544 + 255) / 256, 256, 0, stream>>>(h1pad, IH3, P3, nb);

    k_sift_ang<<<nb * 540, 256, 0, stream>>>(x_c, ang, nHW);
    int nPP = nb * (H + 1) * (W + 1);
    k_sift_pool<<<(nPP + 255) / 256, 256, 0, stream>>>(ang, pooled, nPP);
    k_sift_desc<<<nHW / 4, 256, 0, stream>>>(pooled, spad);

    // conv1 (5x5, 128->64) + fused skip1 (1x1 128->32), 8 waves, 1 block/CU
    k_convr<128, 64, 5, 8, 0, 2, true><<<nbid, 512, 0, stream>>>(
        spad, IH5, P5, wb1, b1, wbs1, sb1, h1raw, sk1, part, nbid);
    k_gn_fin<64, 8><<<nb * 8, 64, 0, stream>>>(part, H, g1w, g1b, sc1, sh1, 1.0f / (8.0f * HW));
    k_norm<64, false><<<nb * 4320, 256, 0, stream>>>(h1raw, nullptr, sc1, sh1, h1pad);

    // conv2 (3x3, 64->32), 2 blocks/CU
    k_convr<64, 32, 3, 8, 0, 4, false><<<nbid, 512, 0, stream>>>(
        h1pad, IH3, P3, wb2, b2, nullptr, nullptr, h2raw, nullptr, part, nbid);
    k_gn_fin<32, 8><<<nb * 8, 64, 0, stream>>>(part, H, g2w, g2b, sc2, sh2, 1.0f / (4.0f * HW));

    // spad dead; its region hosts blkpad + tail buffers
    k_halo<32, 1><<<(nb * 6272 + 255) / 256, 256, 0, stream>>>(blkpad, IH3, P3, nb);
    k_halo<16, 1><<<(nb * 3136 + 255) / 256, 256, 0, stream>>>(h3pad, IH3, P3, nb);
    k_halo<8, 1><<<(nb * 1568 + 255) / 256, 256, 0, stream>>>(blk2, IH3, P3, nb);

    k_norm<32, true><<<nb * 2160, 256, 0, stream>>>(h2raw, sk1, sc2, sh2, blkpad);

    // conv3 (3x3, 32->16), 2 blocks/CU
    k_convr<32, 16, 3, 4, 0, 4, false><<<nbid, 512, 0, stream>>>(
        blkpad, IH3, P3, wb3, b3, nullptr, nullptr, h3raw, nullptr, part, nbid);
    k_gn_fin<16, 4><<<nb * 4, 64, 0, stream>>>(part, H, g3w, g3b, sc3, sh3, 1.0f / (4.0f * HW));
    k_norm<16, false><<<nb * 1080, 256, 0, stream>>>(h3raw, nullptr, sc3, sh3, h3pad);

    k_conv4<<<nb * 540, 256, 0, stream>>>(h3pad, w4, b4, h4raw, part);
    k_gn_fin<8, 4><<<nb * 4, 64, 0, stream>>>(part, 540, g4w, g4b, sc4, sh4, 1.0f / (2.0f * HW));
    k_norm4<<<nb * 540, 256, 0, stream>>>(h4raw, blkpad, sc4, sh4, sw2, sb2, blk2);

    k_conv5<<<nb * 540, 256, 0, stream>>>(blk2, w5, b5, h5);
    k_bilateral<<<nb * 540, 256, 0, stream>>>(h5, x_c, out_c, nHW);
  }
}

// Round 9
// 663.972 us; speedup vs baseline: 1.2757x; 1.0979x over previous
//
#include <hip/hip_runtime.h>

#define DEV __device__ __forceinline__

typedef __bf16 bf16x8 __attribute__((ext_vector_type(8)));
typedef float f32x4 __attribute__((ext_vector_type(4)));

union U8 { uint4 q; unsigned short u[8]; };

constexpr int BN = 4, H = 270, W = 512, HW = H * W;
constexpr int IH5 = 274, P5 = 516;   // pad-2 buffers (SIFT descriptor)
constexpr int IH3 = 272, P3 = 514;   // pad-1 buffers

DEV unsigned short f2bf(float f) {
  unsigned int u = __builtin_bit_cast(unsigned int, f);
  u = (u + 0x7FFFu + ((u >> 16) & 1u)) >> 16;
  return (unsigned short)u;
}
DEV float bf2f(unsigned short h) {
  return __builtin_bit_cast(float, (unsigned int)h << 16);
}

#define GLL16(g, l)                                                                        \
  __builtin_amdgcn_global_load_lds((const __attribute__((address_space(1))) void*)(g),     \
                                   (__attribute__((address_space(3))) void*)(l), 16, 0, 0)

// swizzle: XOR 16B-slot with ((row>>1)&3) -> 2-way (free) bank aliasing on stride-64B reads
DEV int swz(int row) { return ((row >> 1) & 3) << 4; }

// ---------------------------------------------------------------- diagnostic
__global__ void k_fill(float* __restrict__ out, int n, float v) {
  int i = blockIdx.x * 256 + threadIdx.x;
  if (i < n) out[i] = v;
}

// ---------------------------------------------------------------- halo zero
template <int C, int PD>
__global__ void k_halo(unsigned short* __restrict__ buf, int IHt, int pitch, int nb_) {
  int vPerRow = pitch * C / 8;
  int topBot = 2 * PD * vPerRow;
  int sideV = PD * C / 8;
  int midRows = IHt - 2 * PD;
  int perS = topBot + midRows * 2 * sideV;
  int v = blockIdx.x * 256 + threadIdx.x;
  if (v >= nb_ * perS) return;
  int s = v / perS, r = v % perS;
  size_t base = (size_t)s * IHt * pitch * C;
  size_t off;
  if (r < topBot) {
    int half = r / (PD * vPerRow);
    int rr = r % (PD * vPerRow);
    off = ((size_t)(half ? (IHt - PD) : 0) * pitch * C) + (size_t)rr * 8;
  } else {
    int r2 = r - topBot;
    int row = r2 / (2 * sideV), c2 = r2 % (2 * sideV);
    int side = c2 / sideV, cc = c2 % sideV;
    off = ((size_t)(PD + row) * pitch + (side ? (pitch - PD) : 0)) * C + (size_t)cc * 8;
  }
  *(uint4*)(buf + base + off) = uint4{0, 0, 0, 0};
}

// ---------------------------------------------------------------- SIFT stage 1
__global__ void k_sift_ang(const float* __restrict__ x, float* __restrict__ ang, int nTot) {
  int p = blockIdx.x * 256 + threadIdx.x;
  if (p >= nTot) return;
  int b = p / HW, r = p % HW, y = r / W, xx = r % W;
  const float* xb = x + (size_t)b * HW;
  float xm = xb[y * W + (xx > 0 ? xx - 1 : 0)];
  float xp = xb[y * W + (xx < W - 1 ? xx + 1 : W - 1)];
  float ym = xb[(y > 0 ? y - 1 : 0) * W + xx];
  float yp = xb[(y < H - 1 ? y + 1 : H - 1) * W + xx];
  float gx = (xp - xm) * 0.5f, gy = (yp - ym) * 0.5f;
  float mag = sqrtf(gx * gx + gy * gy + 1e-10f);
  float ori = atan2f(gy, gx + 1e-10f) + 6.2831855f;
  float o = (8.0f * ori) / 6.2831855f;
  float bo0f = floorf(o);
  float wo1 = o - bo0f;
  int b0 = ((int)bo0f) & 7;
  int b1 = (b0 + 1) & 7;
  float w0m = (1.0f - wo1) * mag, w1m = wo1 * mag;
  float v[8];
#pragma unroll
  for (int k = 0; k < 8; ++k)
    v[k] = (k == b0 ? w0m : 0.0f) + (k == b1 ? w1m : 0.0f);
  float4* o4 = (float4*)(ang + (size_t)p * 8);
  o4[0] = make_float4(v[0], v[1], v[2], v[3]);
  o4[1] = make_float4(v[4], v[5], v[6], v[7]);
}

// ---------------------------------------------------------------- SIFT stage 2
__global__ void k_sift_pool(const float* __restrict__ ang, float* __restrict__ pooled, int nTot) {
  constexpr int PH = H + 1, PW = W + 1;
  int p = blockIdx.x * 256 + threadIdx.x;
  if (p >= nTot) return;
  int b = p / (PH * PW), r = p % (PH * PW), y = r / PW, xx = r % PW;
  float4 a0 = {0, 0, 0, 0}, a1 = {0, 0, 0, 0};
  const float xc2[4] = {0.5f, 1.5f, 1.5f, 0.5f};
#pragma unroll
  for (int ky = 0; ky < 4; ++ky) {
    int yy = y - 2 + ky;
    if (yy < 0 || yy >= H) continue;
#pragma unroll
    for (int kx = 0; kx < 4; ++kx) {
      int xs = xx - 2 + kx;
      if (xs < 0 || xs >= W) continue;
      float w = xc2[ky] * xc2[kx] * 0.25f;
      const float4* s4 = (const float4*)(ang + ((size_t)(b * H + yy) * W + xs) * 8);
      float4 v0 = s4[0], v1 = s4[1];
      a0.x += w * v0.x; a0.y += w * v0.y; a0.z += w * v0.z; a0.w += w * v0.w;
      a1.x += w * v1.x; a1.y += w * v1.y; a1.z += w * v1.z; a1.w += w * v1.w;
    }
  }
  float4* o4 = (float4*)(pooled + (size_t)p * 8);
  o4[0] = a0; o4[1] = a1;
}

// ---------------------------------------------------------------- SIFT stage 3
// rootsift identity: second l2norm cancels -> out = sqrt(u / max(S,1e-12) + 1e-10)
__global__ void k_sift_desc(const float* __restrict__ pooled, unsigned short* __restrict__ spad) {
  constexpr int PH = H + 1, PW = W + 1;
  int tid = threadIdx.x;
  int wv = tid >> 6, lane = tid & 63;
  int p = blockIdx.x * 4 + wv;
  int b = p / HW, r = p % HW, yy = r / W, xx = r % W;
  int a = lane >> 3, jj = lane & 7;
  int j0 = jj * 2;
  int dy = j0 >> 2, dx = j0 & 3;
  int rr = yy + dy - 1;
  int c0 = xx + dx - 1, c1 = c0 + 1;
  bool rv = (rr >= 0 && rr <= H);
  int rc = min(max(rr, 0), H);
  const float* pb = pooled + ((size_t)(b * PH + rc) * PW) * 8 + a;
  float v0 = 0.0f, v1 = 0.0f;
  if (rv && c0 >= 0 && c0 <= W) v0 = pb[(size_t)c0 * 8];
  if (rv && c1 >= 0 && c1 <= W) v1 = pb[(size_t)c1 * 8];

  float n2 = v0 * v0 + v1 * v1;
#pragma unroll
  for (int m = 1; m < 64; m <<= 1) n2 += __shfl_xor(n2, m);
  float inv = 1.0f / fmaxf(sqrtf(n2), 1e-12f);
  v0 = fminf(v0 * inv, 0.2f);
  v1 = fminf(v1 * inv, 0.2f);
  float S = v0 + v1;
#pragma unroll
  for (int m = 1; m < 64; m <<= 1) S += __shfl_xor(S, m);
  float iS = 1.0f / fmaxf(S, 1e-12f);
  v0 = sqrtf(v0 * iS + 1e-10f);
  v1 = sqrtf(v1 * iS + 1e-10f);
  unsigned int pk = (unsigned int)f2bf(v0) | ((unsigned int)f2bf(v1) << 16);
  *(unsigned int*)(spad + ((size_t)(b * IH5 + yy + 2) * P5 + xx + 2) * 128 + lane * 2) = pk;
}

// ---------------------------------------------------------------- weight prep: [t][co][ci] bf16
template <int CIN, int COUT, int KS>
__global__ void k_prep(const float* __restrict__ w, unsigned short* __restrict__ wbuf) {
  int i = blockIdx.x * 256 + threadIdx.x;
  if (i >= KS * KS * COUT * CIN) return;
  int t = i / (COUT * CIN), r2 = i % (COUT * CIN), co = r2 / CIN, e = r2 % CIN;
  wbuf[i] = f2bf(w[(co * CIN + e) * (KS * KS) + t]);
}

// ---------------------------------------------------------------- bijective XCD remap
DEV int xcd_remap(int bid, int nbid) {
  int q8 = nbid >> 3, r8 = nbid & 7;
  int xcd = bid & 7;
  return (xcd < r8 ? xcd * (q8 + 1) : r8 * (q8 + 1) + (xcd - r8) * q8) + (bid >> 3);
}

// ---------------------------------------------------------------- GLL MFMA conv
// Block = BMPX output px (BMPX/64 waves x 64 px). Padded NHWC input.
// Unit = (ci-quarter q, ky): slab row + W ky-row double-buffered via global_load_lds.
// Optional fused center-tap 1x1 skip.
template <int CIN, int COUT, int KS, int NG, int MINW, bool FSKIP, int BMPX>
__launch_bounds__(BMPX, MINW)
__global__ void k_convr(const unsigned short* __restrict__ in, int IHt, int ipitch,
                        const unsigned short* __restrict__ wtap,
                        const float* __restrict__ bias,
                        const unsigned short* __restrict__ wsk,
                        const float* __restrict__ skb,
                        unsigned short* __restrict__ outraw,
                        unsigned short* __restrict__ skraw,
                        float* __restrict__ part, int nbid) {
  constexpr int NWV = BMPX / 64;
  constexpr int NXB = 512 / BMPX;
  constexpr int SLABPX = BMPX + KS - 1;
  constexpr int KQ = CIN / 32;
  constexpr int NF = COUT / 16;
  constexpr int SLAB = SLABPX * 64;
  constexpr int SWQ = COUT * 64;
  constexpr int SWROW = KS * SWQ;
  constexpr int SSK = FSKIP ? 32 * 64 : 16;
  constexpr int STRIDE = BMPX * 16;
  __shared__ __align__(16) unsigned char slabB[2][SLAB];
  __shared__ __align__(16) unsigned char wrowB[2][SWROW];
  __shared__ __align__(16) unsigned char wskB[2][SSK];
  __shared__ float red[NWV][16];

  int tid = threadIdx.x;
  int lane = tid & 63, wid = tid >> 6;
  int l15 = lane & 15, hi = lane >> 4;

  int byl = xcd_remap(blockIdx.x, nbid);
  int half = byl % NXB, rowid = byl / NXB;
  int y = rowid % H, b = rowid / H;
  int x0 = half * BMPX;

  f32x4 acc[4][NF] = {};
  f32x4 ask[4][2] = {};

  auto stage = [&](int it, int pbuf) {
    int q = it / KS, ky = it % KS;
    const char* src = (const char*)(in + ((size_t)(b * IHt + y + ky) * ipitch + x0) * CIN + q * 32);
    for (int d = tid * 16; d < SLAB; d += STRIDE) {
      int px = d >> 6, qb = d & 63;
      GLL16(src + px * (CIN * 2) + (qb ^ swz(px)), slabB[pbuf] + d);
    }
    const char* wsrc = (const char*)wtap + (size_t)(ky * KS) * (COUT * CIN * 2) + q * 64;
    for (int d = tid * 16; d < SWROW; d += STRIDE) {
      int kx = d / SWQ, rem = d % SWQ;
      int co = rem >> 6, qb = rem & 63;
      GLL16(wsrc + (size_t)kx * (COUT * CIN * 2) + co * (CIN * 2) + (qb ^ swz(co)), wrowB[pbuf] + d);
    }
  };
  auto stage_wsk = [&](int q, int pbuf) {
    const char* src = (const char*)wsk + q * 64;
    for (int d = tid * 16; d < 32 * 64; d += STRIDE) {
      int co = d >> 6, qb = d & 63;
      GLL16(src + co * (CIN * 2) + (qb ^ swz(co)), wskB[pbuf] + d);
    }
  };

  stage(0, 0);
  if constexpr (FSKIP) stage_wsk(0, 0);
  __syncthreads();

#pragma unroll 1
  for (int it = 0; it < KQ * KS; ++it) {
    int cur = it & 1;
    int q = it / KS, ky = it % KS;
    if (it + 1 < KQ * KS) {
      stage(it + 1, cur ^ 1);
      if (FSKIP && (it + 1) % KS == 0) stage_wsk((it + 1) / KS, ((it + 1) / KS) & 1);
    }
    const unsigned char* sl = slabB[cur];
    const unsigned char* wr = wrowB[cur];
    int koff = hi * 16;
#pragma unroll
    for (int kx = 0; kx < KS; ++kx) {
      bf16x8 af[4];
#pragma unroll
      for (int mi = 0; mi < 4; ++mi) {
        int px = wid * 64 + mi * 16 + l15 + kx;
        af[mi] = *(const bf16x8*)(sl + px * 64 + (koff ^ swz(px)));
      }
#pragma unroll
      for (int ni = 0; ni < NF; ++ni) {
        int co = ni * 16 + l15;
        bf16x8 bq = *(const bf16x8*)(wr + kx * SWQ + co * 64 + (koff ^ swz(co)));
#pragma unroll
        for (int mi = 0; mi < 4; ++mi)
          acc[mi][ni] = __builtin_amdgcn_mfma_f32_16x16x32_bf16(af[mi], bq, acc[mi][ni], 0, 0, 0);
      }
      if constexpr (FSKIP) {
        if (ky == KS / 2 && kx == KS / 2) {
#pragma unroll
          for (int ni = 0; ni < 2; ++ni) {
            int co = ni * 16 + l15;
            bf16x8 bq = *(const bf16x8*)(wskB[q & 1] + co * 64 + (koff ^ swz(co)));
#pragma unroll
            for (int mi = 0; mi < 4; ++mi)
              ask[mi][ni] = __builtin_amdgcn_mfma_f32_16x16x32_bf16(af[mi], bq, ask[mi][ni], 0, 0, 0);
          }
        }
      }
    }
    __syncthreads();
  }

#pragma unroll
  for (int ni = 0; ni < NF; ++ni) {
    float bv = bias[ni * 16 + l15];
#pragma unroll
    for (int mi = 0; mi < 4; ++mi)
#pragma unroll
      for (int rr = 0; rr < 4; ++rr)
        acc[mi][ni][rr] += bv;
  }
  unsigned short* op = outraw + ((size_t)(b * H + y) * W + x0) * COUT;
#pragma unroll
  for (int mi = 0; mi < 4; ++mi)
#pragma unroll
    for (int rr = 0; rr < 4; ++rr) {
      int px = wid * 64 + mi * 16 + hi * 4 + rr;
#pragma unroll
      for (int ni = 0; ni < NF; ++ni)
        op[(size_t)px * COUT + ni * 16 + l15] = f2bf(acc[mi][ni][rr]);
    }
  if constexpr (FSKIP) {
    unsigned short* ops = skraw + ((size_t)(b * H + y) * W + x0) * 32;
#pragma unroll
    for (int ni = 0; ni < 2; ++ni) {
      float bv = skb[ni * 16 + l15];
#pragma unroll
      for (int mi = 0; mi < 4; ++mi)
#pragma unroll
        for (int rr = 0; rr < 4; ++rr)
          ask[mi][ni][rr] += bv;
    }
#pragma unroll
    for (int mi = 0; mi < 4; ++mi)
#pragma unroll
      for (int rr = 0; rr < 4; ++rr) {
        int px = wid * 64 + mi * 16 + hi * 4 + rr;
#pragma unroll
        for (int ni = 0; ni < 2; ++ni)
          ops[(size_t)px * 32 + ni * 16 + l15] = f2bf(ask[mi][ni][rr]);
      }
  }
  if constexpr (NG > 0) {
    constexpr int GPC = COUT / NG;
#pragma unroll
    for (int ni = 0; ni < NF; ++ni) {
      float s = 0.0f, q2 = 0.0f;
#pragma unroll
      for (int mi = 0; mi < 4; ++mi)
#pragma unroll
        for (int rr = 0; rr < 4; ++rr) {
          float v = acc[mi][ni][rr];
          s += v; q2 += v * v;
        }
      s += __shfl_xor(s, 16); q2 += __shfl_xor(q2, 16);
      s += __shfl_xor(s, 32); q2 += __shfl_xor(q2, 32);
#pragma unroll
      for (int m = 1; m < GPC; m <<= 1) { s += __shfl_xor(s, m); q2 += __shfl_xor(q2, m); }
      if (hi == 0 && (l15 % GPC) == 0) {
        int g = ni * (16 / GPC) + l15 / GPC;
        red[wid][g] = s;
        red[wid][NG + g] = q2;
      }
    }
    __syncthreads();
    if (tid < 2 * NG) {
      float t = 0.0f;
#pragma unroll
      for (int wv2 = 0; wv2 < NWV; ++wv2) t += red[wv2][tid];
      part[(size_t)byl * (2 * NG) + tid] = t;
    }
  }
}

// ---------------------------------------------------------------- GN finalize
template <int COUT, int NG>
__global__ void k_gn_fin(const float* __restrict__ part, int NB,
                         const float* __restrict__ gw, const float* __restrict__ gb,
                         float* __restrict__ scale, float* __restrict__ shift, float invN) {
  constexpr int GPC = COUT / NG;
  int b = blockIdx.x / NG, g = blockIdx.x % NG;
  int lane = threadIdx.x;
  float s = 0.0f, q = 0.0f;
  for (int i = lane; i < NB; i += 64) {
    const float* pp = part + (size_t)(b * NB + i) * (2 * NG);
    s += pp[g]; q += pp[NG + g];
  }
#pragma unroll
  for (int m = 1; m < 64; m <<= 1) { s += __shfl_xor(s, m); q += __shfl_xor(q, m); }
  if (lane == 0) {
    float mean = s * invN;
    float var = q * invN - mean * mean;
    float rstd = rsqrtf(var + 1e-5f);
#pragma unroll
    for (int j = 0; j < GPC; ++j) {
      int c = g * GPC + j;
      float sc = gw[c] * rstd;
      scale[b * COUT + c] = sc;
      shift[b * COUT + c] = gb[c] - mean * sc;
    }
  }
}

// ---------------------------------------------------------------- GN-apply (+ReLU, +skip)
template <int C, bool ADDSKIP>
__global__ void k_norm(const unsigned short* __restrict__ raw,
                       const unsigned short* __restrict__ skip,
                       const float* __restrict__ scale, const float* __restrict__ shift,
                       unsigned short* __restrict__ outpad) {
  int e = blockIdx.x * 256 + threadIdx.x;
  int idx = e * 8;
  int p = idx / C, c0 = idx % C;
  int b = p / HW, r = p % HW, y = r / W, xx = r % W;
  U8 v; v.q = *(const uint4*)(raw + (size_t)p * C + c0);
  U8 sk;
  if (ADDSKIP) sk.q = *(const uint4*)(skip + (size_t)p * C + c0);
  const float* sc = scale + b * C + c0;
  const float* sh = shift + b * C + c0;
  U8 o;
#pragma unroll
  for (int j = 0; j < 8; ++j) {
    float f = fmaxf(bf2f(v.u[j]) * sc[j] + sh[j], 0.0f);
    if (ADDSKIP) f += bf2f(sk.u[j]);
    o.u[j] = f2bf(f);
  }
  *(uint4*)(outpad + ((size_t)(b * IH3 + y + 1) * P3 + xx + 1) * C + c0) = o.q;
}

// ---------------------------------------------------------------- conv4 direct (16->8, 3x3), fused gn3+relu on input
__global__ void k_conv4(const unsigned short* __restrict__ h3raw, const float* __restrict__ w4,
                        const float* __restrict__ b4,
                        const float* __restrict__ sc3, const float* __restrict__ sh3,
                        unsigned short* __restrict__ h4raw, float* __restrict__ part) {
  __shared__ float wl[1152];
  __shared__ float scs[16], shs[16];
  __shared__ float red[4][8];
  int b0 = (blockIdx.x * 256) / HW;
  for (int i = threadIdx.x; i < 1152; i += 256) {
    int t = i / 128, r2 = i % 128, ci = r2 >> 3, co = r2 & 7;
    wl[i] = w4[(co * 16 + ci) * 9 + t];
  }
  if (threadIdx.x < 16) { scs[threadIdx.x] = sc3[b0 * 16 + threadIdx.x]; shs[threadIdx.x] = sh3[b0 * 16 + threadIdx.x]; }
  __syncthreads();
  int p = blockIdx.x * 256 + threadIdx.x;
  int b = p / HW, r = p % HW, y = r / W, xx = r % W;
  float acc[8];
#pragma unroll
  for (int co = 0; co < 8; ++co) acc[co] = b4[co];
#pragma unroll
  for (int t = 0; t < 9; ++t) {
    int ky = t / 3, kx = t % 3;
    int row = y + ky - 1, x = xx + kx - 1;
    if (row < 0 || row >= H || x < 0 || x >= W) continue;
    const unsigned short* ip = h3raw + ((size_t)(b * H + row) * W + x) * 16;
    U8 u0, u1;
    u0.q = *(const uint4*)ip;
    u1.q = *(const uint4*)(ip + 8);
#pragma unroll
    for (int ci = 0; ci < 16; ++ci) {
      float raw = bf2f(ci < 8 ? u0.u[ci] : u1.u[ci - 8]);
      float iv = fmaxf(raw * scs[ci] + shs[ci], 0.0f);
#pragma unroll
      for (int co = 0; co < 8; ++co)
        acc[co] += iv * wl[t * 128 + ci * 8 + co];
    }
  }
  int lane = threadIdx.x & 63, wv = threadIdx.x >> 6;
  float s[4], q[4];
#pragma unroll
  for (int g = 0; g < 4; ++g) {
    s[g] = acc[2 * g] + acc[2 * g + 1];
    q[g] = acc[2 * g] * acc[2 * g] + acc[2 * g + 1] * acc[2 * g + 1];
  }
#pragma unroll
  for (int m = 1; m < 64; m <<= 1) {
#pragma unroll
    for (int g = 0; g < 4; ++g) { s[g] += __shfl_xor(s[g], m); q[g] += __shfl_xor(q[g], m); }
  }
  if (lane == 0) {
#pragma unroll
    for (int g = 0; g < 4; ++g) { red[wv][g] = s[g]; red[wv][4 + g] = q[g]; }
  }
  __syncthreads();
  if (threadIdx.x < 8)
    part[(size_t)blockIdx.x * 8 + threadIdx.x] =
        red[0][threadIdx.x] + red[1][threadIdx.x] + red[2][threadIdx.x] + red[3][threadIdx.x];
  U8 o;
#pragma unroll
  for (int co = 0; co < 8; ++co) o.u[co] = f2bf(acc[co]);
  *(uint4*)(h4raw + (size_t)p * 8) = o.q;
}

// ---------------------------------------------------------------- norm4 + skip2 (1x1 32->8), blkpad-based (round-7 proven)
__global__ void k_norm4(const unsigned short* __restrict__ h4raw, const unsigned short* __restrict__ blkpad,
                        const float* __restrict__ scale, const float* __restrict__ shift,
                        const float* __restrict__ sw2, const float* __restrict__ sb2,
                        unsigned short* __restrict__ blk2pad) {
  __shared__ float wl[256];
  {
    int i = threadIdx.x;
    int ci = i >> 3, co = i & 7;
    wl[i] = sw2[co * 32 + ci];
  }
  __syncthreads();
  int p = blockIdx.x * 256 + threadIdx.x;
  int b = p / HW, r = p % HW, y = r / W, xx = r % W;
  float acc[8];
#pragma unroll
  for (int co = 0; co < 8; ++co) acc[co] = sb2[co];
  size_t cbase = ((size_t)(b * IH3 + y + 1) * P3 + (xx + 1));
  const unsigned short* bp = blkpad + cbase * 32;
#pragma unroll
  for (int half = 0; half < 4; ++half) {
    U8 u; u.q = *(const uint4*)(bp + half * 8);
#pragma unroll
    for (int j = 0; j < 8; ++j) {
      float iv = bf2f(u.u[j]);
      int ci = half * 8 + j;
#pragma unroll
      for (int co = 0; co < 8; ++co) acc[co] += iv * wl[ci * 8 + co];
    }
  }
  U8 hv; hv.q = *(const uint4*)(h4raw + (size_t)p * 8);
  U8 o;
#pragma unroll
  for (int co = 0; co < 8; ++co) {
    float f = fmaxf(bf2f(hv.u[co]) * scale[b * 8 + co] + shift[b * 8 + co], 0.0f) + acc[co];
    o.u[co] = f2bf(f);
  }
  *(uint4*)(blk2pad + cbase * 8) = o.q;
}

// ---------------------------------------------------------------- conv5 direct (8->2, 3x3)
__global__ void k_conv5(const unsigned short* __restrict__ blk2pad, const float* __restrict__ w5,
                        const float* __restrict__ b5, float* __restrict__ h5) {
  __shared__ float wl[144];
  if (threadIdx.x < 144) {
    int i = threadIdx.x;
    int t = i / 16, r2 = i % 16, ci = r2 >> 1, co = r2 & 1;
    wl[i] = w5[(co * 8 + ci) * 9 + t];
  }
  __syncthreads();
  int p = blockIdx.x * 256 + threadIdx.x;
  int b = p / HW, r = p % HW, y = r / W, xx = r % W;
  float a0 = b5[0], a1 = b5[1];
#pragma unroll
  for (int t = 0; t < 9; ++t) {
    int ky = t / 3, kx = t % 3;
    const unsigned short* ip = blk2pad + ((size_t)(b * IH3 + y + ky) * P3 + (xx + kx)) * 8;
    U8 u; u.q = *(const uint4*)ip;
#pragma unroll
    for (int ci = 0; ci < 8; ++ci) {
      float iv = bf2f(u.u[ci]);
      a0 += iv * wl[t * 16 + ci * 2];
      a1 += iv * wl[t * 16 + ci * 2 + 1];
    }
  }
  h5[(size_t)p * 2] = a0;
  h5[(size_t)p * 2 + 1] = a1;
}

// ---------------------------------------------------------------- joint bilateral + tanh + scale
__global__ void k_bilateral(const float* __restrict__ h5, const float* __restrict__ x,
                            float* __restrict__ out, int nTot) {
  int p = blockIdx.x * 256 + threadIdx.x;
  if (p >= nTot) return;
  int b = p / HW, r = p % HW, y = r / W, xx = r % W;
  const float* xb = x + (size_t)b * HW;
  float xc = xb[r];
  float e1 = expf(-1.0f / 4.5f), e0 = expf(-4.0f / 4.5f);
  float gs = 1.0f + 2.0f * e1 + 2.0f * e0;
  float g[5] = {e0 / gs, e1 / gs, 1.0f / gs, e1 / gs, e0 / gs};
  float n0 = 0.0f, n1 = 0.0f, den = 0.0f;
#pragma unroll
  for (int dy = 0; dy < 5; ++dy) {
    int yn = y + dy - 2;
    yn = yn < 0 ? -yn : (yn >= H ? 2 * H - 2 - yn : yn);
#pragma unroll
    for (int dx = 0; dx < 5; ++dx) {
      int xn = xx + dx - 2;
      xn = xn < 0 ? -xn : (xn >= W ? 2 * W - 2 - xn : xn);
      float xv = xb[yn * W + xn];
      float d = xv - xc;
      float wgt = g[dy] * g[dx] * expf(-200.0f * d * d);
      den += wgt;
      const float* hp = h5 + ((size_t)(b * HW) + yn * W + xn) * 2;
      n0 += wgt * hp[0];
      n1 += wgt * hp[1];
    }
  }
  float o0 = tanhf(n0 / den) * 0.436f;
  float o1 = tanhf(n1 / den) * 0.615f;
  out[(size_t)(b * 2) * HW + r] = o0;
  out[(size_t)(b * 2 + 1) * HW + r] = o1;
}

// ---------------------------------------------------------------- host
extern "C" void kernel_launch(void* const* d_in, const int* in_sizes, int n_in,
                              void* d_out, int out_size, void* d_ws, size_t ws_size,
                              hipStream_t stream) {
  (void)in_sizes; (void)n_in; (void)out_size;
  const float* x   = (const float*)d_in[0];
  const float* w1  = (const float*)d_in[1];
  const float* b1  = (const float*)d_in[2];
  const float* g1w = (const float*)d_in[3];
  const float* g1b = (const float*)d_in[4];
  const float* w2  = (const float*)d_in[5];
  const float* b2  = (const float*)d_in[6];
  const float* g2w = (const float*)d_in[7];
  const float* g2b = (const float*)d_in[8];
  const float* w3  = (const float*)d_in[9];
  const float* b3  = (const float*)d_in[10];
  const float* g3w = (const float*)d_in[11];
  const float* g3b = (const float*)d_in[12];
  const float* w4  = (const float*)d_in[13];
  const float* b4  = (const float*)d_in[14];
  const float* g4w = (const float*)d_in[15];
  const float* g4b = (const float*)d_in[16];
  const float* w5  = (const float*)d_in[17];
  const float* b5  = (const float*)d_in[18];
  const float* sw1 = (const float*)d_in[19];
  const float* sb1 = (const float*)d_in[20];
  const float* sw2 = (const float*)d_in[21];
  const float* sb2 = (const float*)d_in[22];
  float* out = (float*)d_out;
  char* ws = (char*)d_ws;

  auto AL = [](size_t v) { return (v + 255) & ~(size_t)255; };
  const size_t sSPAD  = (size_t)IH5 * P5 * 128 * 2;
  const size_t sANG   = (size_t)HW * 8 * 4;
  const size_t sH1RAW = (size_t)HW * 64 * 2;
  const size_t sH1PAD = (size_t)IH3 * P3 * 64 * 2;
  const size_t sH2RAW = (size_t)HW * 32 * 2;
  const size_t sBLKP  = (size_t)IH3 * P3 * 32 * 2;
  const size_t sH3RAW = (size_t)HW * 16 * 2;
  const size_t sH3PAD = (size_t)IH3 * P3 * 16 * 2;
  const size_t sH4RAW = (size_t)HW * 8 * 2;
  const size_t sBLK2  = (size_t)IH3 * P3 * 8 * 2;

  int nb = 0;
  size_t offB = 0, offH1PAD = 0, offSmall = 0;
  const size_t smallFixed = AL(1024 * 1024) + AL((size_t)4 * 1080 * 16 * 4) + 8 * 4096;
  for (int cand = 4; cand >= 1; cand >>= 1) {
    size_t oB   = AL((size_t)cand * sSPAD);
    size_t oH1P = AL(oB + (size_t)cand * sH1RAW);
    size_t oS   = AL(oH1P + (size_t)cand * sH1PAD);
    size_t need = oS + smallFixed + AL((size_t)cand * sH2RAW);
    if (ws_size >= need) { nb = cand; offB = oB; offH1PAD = oH1P; offSmall = oS; break; }
  }
  if (nb == 0) {
    k_fill<<<(BN * 2 * HW + 255) / 256, 256, 0, stream>>>(out, BN * 2 * HW, 123.0f);
    return;
  }

  size_t oWB1  = offSmall;
  size_t oWB2  = AL(oWB1 + 25 * 64 * 128 * 2);
  size_t oWB3  = AL(oWB2 + 9 * 32 * 64 * 2);
  size_t oWBS  = AL(oWB3 + 9 * 16 * 32 * 2);
  size_t oPART = AL(oWBS + 32 * 128 * 2);
  size_t oSC1  = AL(oPART + (size_t)4 * 1080 * 16 * 4);
  size_t oSC2  = oSC1 + 4096, oSC3 = oSC2 + 4096, oSC4 = oSC3 + 4096;
  size_t oSK1  = oSC4 + 4096;

  unsigned short* wb1  = (unsigned short*)(ws + oWB1);
  unsigned short* wb2  = (unsigned short*)(ws + oWB2);
  unsigned short* wb3  = (unsigned short*)(ws + oWB3);
  unsigned short* wbs1 = (unsigned short*)(ws + oWBS);
  float* part = (float*)(ws + oPART);
  float* sc1 = (float*)(ws + oSC1); float* sh1 = sc1 + nb * 64;
  float* sc2 = (float*)(ws + oSC2); float* sh2 = sc2 + nb * 32;
  float* sc3 = (float*)(ws + oSC3); float* sh3 = sc3 + nb * 16;
  float* sc4 = (float*)(ws + oSC4); float* sh4 = sc4 + nb * 8;
  unsigned short* sk1 = (unsigned short*)(ws + oSK1);

  k_prep<128, 64, 5><<<800, 256, 0, stream>>>(w1, wb1);
  k_prep<64, 32, 3><<<72, 256, 0, stream>>>(w2, wb2);
  k_prep<32, 16, 3><<<18, 256, 0, stream>>>(w3, wb3);
  k_prep<128, 32, 1><<<16, 256, 0, stream>>>(sw1, wbs1);

  size_t t0 = AL((size_t)nb * sBLKP);
  size_t t1 = AL(t0 + (size_t)nb * sH3RAW);
  size_t t2 = AL(t1 + (size_t)nb * sH3PAD);
  size_t t3 = AL(t2 + (size_t)nb * sH4RAW);
  size_t t4 = AL(t3 + (size_t)nb * sBLK2);

  for (int b0 = 0; b0 < BN; b0 += nb) {
    const float* x_c = x + (size_t)b0 * HW;
    float* out_c = out + (size_t)b0 * 2 * HW;
    unsigned short* spad   = (unsigned short*)(ws);
    float*          ang    = (float*)(ws + offB);
    float*          pooled = (float*)(ws + AL(offB + (size_t)nb * sANG));
    unsigned short* h1raw  = (unsigned short*)(ws + offB);
    unsigned short* h1pad  = (unsigned short*)(ws + offH1PAD);
    unsigned short* h2raw  = (unsigned short*)(ws + offB);
    unsigned short* blkpad = (unsigned short*)(ws);
    unsigned short* h3raw  = (unsigned short*)(ws + t0);
    unsigned short* h4raw  = (unsigned short*)(ws + t2);
    unsigned short* blk2   = (unsigned short*)(ws + t3);
    float*          h5     = (float*)(ws + t4);
    int nHW = nb * HW;

    // halo-only zeroing (interiors fully overwritten each chunk)
    k_halo<128, 2><<<(nb * 50304 + 255) / 256, 256, 0, stream>>>(spad, IH5, P5, nb);
    k_halo<64, 1><<<(nb * 12544 + 255) / 256, 256, 0, stream>>>(h1pad, IH3, P3, nb);

    k_sift_ang<<<nb * 540, 256, 0, stream>>>(x_c, ang, nHW);
    int nPP = nb * (H + 1) * (W + 1);
    k_sift_pool<<<(nPP + 255) / 256, 256, 0, stream>>>(ang, pooled, nPP);
    k_sift_desc<<<nHW / 4, 256, 0, stream>>>(pooled, spad);

    // conv1 (5x5, 128->64) + fused skip1 (1x1 128->32): half-row blocks, 2 blk/CU
    int n1 = nb * H * 2;
    k_convr<128, 64, 5, 8, 2, true, 256><<<n1, 256, 0, stream>>>(
        spad, IH5, P5, wb1, b1, wbs1, sb1, h1raw, sk1, part, n1);
    k_gn_fin<64, 8><<<nb * 8, 64, 0, stream>>>(part, 2 * H, g1w, g1b, sc1, sh1, 1.0f / (8.0f * HW));
    k_norm<64, false><<<nb * 4320, 256, 0, stream>>>(h1raw, nullptr, sc1, sh1, h1pad);

    // conv2 (3x3, 64->32), full-row 512-thr (round-7 proven path)
    int n2 = nb * H;
    k_convr<64, 32, 3, 8, 4, false, 512><<<n2, 512, 0, stream>>>(
        h1pad, IH3, P3, wb2, b2, nullptr, nullptr, h2raw, nullptr, part, n2);
    k_gn_fin<32, 8><<<nb * 8, 64, 0, stream>>>(part, H, g2w, g2b, sc2, sh2, 1.0f / (4.0f * HW));

    // spad dead; its region hosts blkpad + tail buffers
    k_halo<32, 1><<<(nb * 6272 + 255) / 256, 256, 0, stream>>>(blkpad, IH3, P3, nb);
    k_halo<8, 1><<<(nb * 1568 + 255) / 256, 256, 0, stream>>>(blk2, IH3, P3, nb);

    k_norm<32, true><<<nb * 2160, 256, 0, stream>>>(h2raw, sk1, sc2, sh2, blkpad);

    // conv3 (3x3, 32->16), full-row 512-thr
    k_convr<32, 16, 3, 4, 4, false, 512><<<n2, 512, 0, stream>>>(
        blkpad, IH3, P3, wb3, b3, nullptr, nullptr, h3raw, nullptr, part, n2);
    k_gn_fin<16, 4><<<nb * 4, 64, 0, stream>>>(part, H, g3w, g3b, sc3, sh3, 1.0f / (4.0f * HW));

    // conv4 (3x3, 16->8), fused gn3+relu on input (bounds-checked zero-pad)
    k_conv4<<<nb * 540, 256, 0, stream>>>(h3raw, w4, b4, sc3, sh3, h4raw, part);
    k_gn_fin<8, 4><<<nb * 4, 64, 0, stream>>>(part, 540, g4w, g4b, sc4, sh4, 1.0f / (2.0f * HW));

    k_norm4<<<nb * 540, 256, 0, stream>>>(h4raw, blkpad, sc4, sh4, sw2, sb2, blk2);

    k_conv5<<<nb * 540, 256, 0, stream>>>(blk2, w5, b5, h5);
    k_bilateral<<<nb * 540, 256, 0, stream>>>(h5, x_c, out_c, nHW);
  }
}